// Round 3
// baseline (1031.233 us; speedup 1.0000x reference)
//
#include <hip/hip_runtime.h>
#include <math.h>

// ---------------------------------------------------------------------------
// CrossGroupedQueryAttention on MI355X — round 3
//
// R2 post-mortem: k1_stats was 282us with WRITE_SIZE 564MB vs 203MB ideal
// (2.8x write amplification): per-thread writes at 768B row stride left 64B
// lines partially dirty past L2 eviction. This round: wave-coalesced writes
// (lane l -> pixel l>>4, chunk l&15; 256B contiguous per 16-lane group) with
// LN stats reduced via 16-wide shfl_xor. Reads become 16x16B-segment
// gathers but stay L1-resident per block (24KB/iter).
// ---------------------------------------------------------------------------

typedef unsigned short u16;
typedef unsigned int u32;
typedef short s16x8 __attribute__((ext_vector_type(8)));
typedef float f32x4 __attribute__((ext_vector_type(4)));

#define HW 16384
#define NB 8
#define CDIM 384
#define KVC 192

__device__ __forceinline__ float b2f(u16 u) {
  return __uint_as_float(((u32)u) << 16);
}
__device__ __forceinline__ u16 f2b(float f) {
  u32 u = __float_as_uint(f);
  u += 0x7fffu + ((u >> 16) & 1u);   // RNE
  return (u16)(u >> 16);
}

// ---------------------------------------------------------------------------
// k0: fold LN weights into conv weights.  1024 threads.
// ---------------------------------------------------------------------------
__global__ void k0_prep(const float* __restrict__ wq, const float* __restrict__ wkv,
                        const float* __restrict__ wo,
                        const float* __restrict__ lnqw, const float* __restrict__ lnqb,
                        const float* __restrict__ lnkw, const float* __restrict__ lnkb,
                        u16* __restrict__ wqp, float* __restrict__ rwsQ, float* __restrict__ biasQ,
                        u16* __restrict__ wkvp, float* __restrict__ rwsKV, float* __restrict__ biasKV,
                        u16* __restrict__ wop) {
  int r = blockIdx.x * 256 + threadIdx.x;
  if (r < 384) {
    float rs = 0.f, bs = 0.f;
    for (int i = 0; i < 384; ++i) {
      float wp = wq[r * 384 + i] * lnqw[i];
      u16 h = f2b(wp);
      rs += b2f(h);
      bs += wq[r * 384 + i] * lnqb[i];
      wqp[r * 384 + i] = h;
    }
    rwsQ[r] = rs; biasQ[r] = bs;
  } else if (r < 640) {
    int o = r - 384;
    if (o < 192) {
      float rs = 0.f, bs = 0.f;
      for (int i = 0; i < 384; ++i) {
        float wp = wkv[o * 384 + i] * lnkw[i];
        u16 h = f2b(wp);
        rs += b2f(h);
        bs += wkv[o * 384 + i] * lnkb[i];
        wkvp[o * 384 + i] = h;
      }
      rwsKV[o] = rs; biasKV[o] = bs;
    } else {
      for (int i = 0; i < 384; ++i) wkvp[o * 384 + i] = 0;
      rwsKV[o] = 0.f; biasKV[o] = 0.f;
    }
  } else {
    int o = r - 640;
    for (int i = 0; i < 384; ++i) wop[o * 384 + i] = f2b(wo[o * 384 + i]);
  }
}

// ---------------------------------------------------------------------------
// k1: LN stats per pixel + transpose f32 [c][p] -> bf16 [p][c].
// grid (64, 8, 2), 256 thr. Wave-coalesced writes: lane l of a wave handles
// pixel (i*16 + w*4 + (l>>4)) and chunks c8 = (l&15)+16j. Each store instr
// covers 4 rows x 256B contiguous -> fully-dirty 64B lines.
// ---------------------------------------------------------------------------
__global__ __launch_bounds__(256) void k1_stats(const float* __restrict__ q, const float* __restrict__ k,
                                                u16* __restrict__ qt, u16* __restrict__ kt,
                                                float* __restrict__ muQ, float* __restrict__ sdQ,
                                                float* __restrict__ muK, float* __restrict__ sdK) {
  int t = blockIdx.z;
  const float* src = t ? k : q;
  u16* dst = t ? kt : qt;
  float* mu = t ? muK : muQ;
  float* sd = t ? sdK : sdQ;
  int b = blockIdx.y;
  int tid = threadIdx.x;
  int w = tid >> 6, l = tid & 63;
  int lc = l & 15;    // channel-chunk sub-index
  int lp = l >> 4;    // pixel sub-index 0..3
  size_t cbase = (size_t)b * CDIM * HW;

  for (int i = 0; i < 16; ++i) {
    int p = blockIdx.x * 256 + i * 16 + w * 4 + lp;
    float sum = 0.f, sq = 0.f;
    u32 pk[3][4];
#pragma unroll
    for (int j = 0; j < 3; ++j) {
      int c8 = lc + 16 * j;
#pragma unroll
      for (int e = 0; e < 8; ++e) {
        float v = src[cbase + (size_t)(c8 * 8 + e) * HW + p];
        sum += v; sq += v * v;
        u16 h = f2b(v);
        if (e & 1) pk[j][e >> 1] |= ((u32)h) << 16; else pk[j][e >> 1] = (u32)h;
      }
    }
    uint4* dv = (uint4*)dst + ((size_t)(b * HW + p)) * 48;
#pragma unroll
    for (int j = 0; j < 3; ++j)
      dv[lc + 16 * j] = make_uint4(pk[j][0], pk[j][1], pk[j][2], pk[j][3]);
    // reduce stats across the 16-lane channel group
#pragma unroll
    for (int m = 1; m < 16; m <<= 1) {
      sum += __shfl_xor(sum, m, 16);
      sq  += __shfl_xor(sq,  m, 16);
    }
    if (lc == 0) {
      float mn = sum * (1.f / 384.f);
      float var = sq * (1.f / 384.f) - mn * mn;
      mu[b * HW + p] = mn;
      sd[b * HW + p] = rsqrtf(var + 1e-5f);
    }
  }
}

// ---------------------------------------------------------------------------
// BT-GEMM: D[o][p] = sum_k A[o][k] * Bt[p][k], K=384.
// ---------------------------------------------------------------------------
template <int MODE>
__global__ __launch_bounds__(256) void gemm_bt(const u16* __restrict__ A,
                                               const u16* __restrict__ Bt,
                                               const float* __restrict__ rowsum,
                                               const float* __restrict__ bias,
                                               const float* __restrict__ mu,
                                               const float* __restrict__ rstd,
                                               void* __restrict__ outv, int M) {
  int b = blockIdx.z, ot = blockIdx.y, pt = blockIdx.x;
  int tid = threadIdx.x;
  int w = tid >> 6, l = tid & 63;
  int wm = w >> 1, wn = w & 1;
  int lr = l & 15, lg = l >> 4;

  f32x4 acc[4][4] = {};
  int arow0 = ot * 128 + wm * 64 + lr;
  size_t brow0 = (size_t)(b * HW + pt * 128 + wn * 64 + lr);

  for (int ks = 0; ks < 12; ++ks) {
    int ko = ks * 32 + lg * 8;
    s16x8 a[4], bb[4];
#pragma unroll
    for (int mf = 0; mf < 4; ++mf)
      a[mf] = *(const s16x8*)(A + (size_t)(arow0 + mf * 16) * 384 + ko);
#pragma unroll
    for (int nf = 0; nf < 4; ++nf)
      bb[nf] = *(const s16x8*)(Bt + (brow0 + nf * 16) * 384 + ko);
#pragma unroll
    for (int mf = 0; mf < 4; ++mf)
#pragma unroll
      for (int nf = 0; nf < 4; ++nf)
        acc[mf][nf] = __builtin_amdgcn_mfma_f32_16x16x32_bf16(a[mf], bb[nf], acc[mf][nf], 0, 0, 0);
  }

#pragma unroll
  for (int nf = 0; nf < 4; ++nf) {
    int p = pt * 128 + wn * 64 + nf * 16 + lr;
    float m_ = 0.f, s_ = 0.f;
    if (MODE == 0) { int pi = b * HW + p; m_ = mu[pi]; s_ = rstd[pi]; }
#pragma unroll
    for (int mf = 0; mf < 4; ++mf) {
#pragma unroll
      for (int r = 0; r < 4; ++r) {
        int o = ot * 128 + wm * 64 + mf * 16 + lg * 4 + r;
        if (MODE == 0) {
          if (o < M) {
            float v = s_ * (acc[mf][nf][r] - m_ * rowsum[o]) + bias[o];
            ((u16*)outv)[((size_t)(b * M + o)) * HW + p] = f2b(v);
          }
        } else {
          ((float*)outv)[((size_t)(b * CDIM + o)) * HW + p] = acc[mf][nf][r];
        }
      }
    }
  }
}

// ---------------------------------------------------------------------------
// k4: depthwise 3x3 (zero pad), LDS-staged plane + fused row l2-norm.
// ---------------------------------------------------------------------------
__global__ __launch_bounds__(256) void k4_dw(const u16* __restrict__ qp, const u16* __restrict__ kvp,
                                             const float* __restrict__ wqdw, const float* __restrict__ wkvdw,
                                             u16* __restrict__ qd, u16* __restrict__ kvd,
                                             float* __restrict__ rnq, float* __restrict__ rnk) {
  __shared__ u16 plane[16384];     // 32 KB
  __shared__ float red[256];

  int c = blockIdx.x, b = blockIdx.y;
  int tid = threadIdx.x;
  const u16* in; u16* outb; const float* wp; int C;
  int isQ = (c < 384), cc = isQ ? c : c - 384;
  if (isQ) { in = qp; outb = qd; wp = wqdw + cc * 9; C = CDIM; }
  else     { in = kvp; outb = kvd; wp = wkvdw + cc * 9; C = KVC; }
  size_t base = ((size_t)(b * C + cc)) * HW;

  float w[9];
#pragma unroll
  for (int j = 0; j < 9; ++j) w[j] = wp[j];

  const uint4* gsrc = (const uint4*)(in + base);
  uint4* lplane = (uint4*)plane;
#pragma unroll
  for (int i = 0; i < 8; ++i) lplane[tid + i * 256] = gsrc[tid + i * 256];
  __syncthreads();

  uint4* gdst = (uint4*)(outb + base);
  float ns = 0.f;
#pragma unroll
  for (int it = 0; it < 8; ++it) {
    int idx = tid + it * 256;
    int y = idx >> 4, ox = idx & 15;
    int x0 = ox * 8;

    float r[3][10];
#pragma unroll
    for (int rr = 0; rr < 3; ++rr) {
      int yy = y + rr - 1;
      if ((unsigned)yy < 128u) {
        int rbase = yy * 128 + x0;
        r[rr][0] = (x0 > 0) ? b2f(plane[rbase - 1]) : 0.f;
        uint4 v = *(const uint4*)&plane[rbase];
        u32 ws[4] = {v.x, v.y, v.z, v.w};
#pragma unroll
        for (int j = 0; j < 4; ++j) {
          r[rr][1 + 2 * j] = b2f((u16)(ws[j] & 0xffff));
          r[rr][2 + 2 * j] = b2f((u16)(ws[j] >> 16));
        }
        r[rr][9] = (x0 < 120) ? b2f(plane[rbase + 8]) : 0.f;
      } else {
#pragma unroll
        for (int j = 0; j < 10; ++j) r[rr][j] = 0.f;
      }
    }

    u32 packed[4];
#pragma unroll
    for (int j = 0; j < 8; ++j) {
      float a = 0.f;
#pragma unroll
      for (int rr = 0; rr < 3; ++rr)
#pragma unroll
        for (int dx = 0; dx < 3; ++dx)
          a += w[rr * 3 + dx] * r[rr][j + dx];
      u16 h = f2b(a);
      float hv = b2f(h);
      ns += hv * hv;
      if (j & 1) packed[j >> 1] |= ((u32)h) << 16; else packed[j >> 1] = (u32)h;
    }
    gdst[idx] = make_uint4(packed[0], packed[1], packed[2], packed[3]);
  }

  red[tid] = ns;
  __syncthreads();
  for (int st = 128; st > 0; st >>= 1) {
    if (tid < st) red[tid] += red[tid + st];
    __syncthreads();
  }
  if (tid == 0) {
    float n = sqrtf(red[0]);
    float inv = 1.f / fmaxf(n, 1e-12f);
    if (isQ) rnq[b * 384 + cc] = inv;
    else if (cc < 96) rnk[b * 96 + cc] = inv;
  }
}

// ---------------------------------------------------------------------------
// k5b: transpose v (kvd rows 96..191) -> vt [b][p][96] bf16. grid (64, 8).
// ---------------------------------------------------------------------------
__global__ void k5b_vt(const u16* __restrict__ kvd, u16* __restrict__ vt) {
  int p = blockIdx.x * 256 + threadIdx.x;
  int b = blockIdx.y;
  size_t sb = ((size_t)(b * KVC + 96)) * HW + p;
  uint4* dv = (uint4*)vt + ((size_t)(b * HW + p)) * 12;
  for (int j8 = 0; j8 < 12; ++j8) {
    u32 w[4];
#pragma unroll
    for (int j = 0; j < 8; ++j) {
      u16 h = kvd[sb + (size_t)(j8 * 8 + j) * HW];
      if (j & 1) w[j >> 1] |= ((u32)h) << 16; else w[j >> 1] = (u32)h;
    }
    dv[j8] = make_uint4(w[0], w[1], w[2], w[3]);
  }
}

// ---------------------------------------------------------------------------
// k6: split-K QK^T partials. grid (16, 8, 8).
// ---------------------------------------------------------------------------
__global__ __launch_bounds__(256) void k6_qk(const u16* __restrict__ qd,
                                             const u16* __restrict__ kvd,
                                             float* __restrict__ spart) {
  int kc = blockIdx.x, h = blockIdx.y, b = blockIdx.z;
  int tid = threadIdx.x;
  int w = tid >> 6, l = tid & 63, lr = l & 15, lg = l >> 4;
  int g = h >> 2;
  int p0 = kc * 1024 + w * 256;

  f32x4 acc[3][3] = {};
  size_t qbase = ((size_t)(b * CDIM + h * 48 + lr)) * HW;
  size_t kbase = ((size_t)(b * KVC + g * 48 + lr)) * HW;

  for (int ks = 0; ks < 8; ++ks) {
    int pp = p0 + ks * 32 + lg * 8;
    s16x8 a[3], bb[3];
#pragma unroll
    for (int mi = 0; mi < 3; ++mi) a[mi] = *(const s16x8*)(qd + qbase + (size_t)mi * 16 * HW + pp);
#pragma unroll
    for (int ni = 0; ni < 3; ++ni) bb[ni] = *(const s16x8*)(kvd + kbase + (size_t)ni * 16 * HW + pp);
#pragma unroll
    for (int mi = 0; mi < 3; ++mi)
#pragma unroll
      for (int ni = 0; ni < 3; ++ni)
        acc[mi][ni] = __builtin_amdgcn_mfma_f32_16x16x32_bf16(a[mi], bb[ni], acc[mi][ni], 0, 0, 0);
  }

  size_t sb = ((size_t)((((b * 8 + h) * 16) + kc) * 4 + w)) * 2304;
#pragma unroll
  for (int mi = 0; mi < 3; ++mi)
#pragma unroll
    for (int ni = 0; ni < 3; ++ni)
#pragma unroll
      for (int r = 0; r < 4; ++r) {
        int c = mi * 16 + lg * 4 + r, d = ni * 16 + lr;
        spart[sb + c * 48 + d] = acc[mi][ni][r];
      }
}

// ---------------------------------------------------------------------------
// k7: reduce partials + scale + softmax -> P~ [b][384][96] bf16.
// ---------------------------------------------------------------------------
__global__ void k7_sm(const float* __restrict__ spart, const float* __restrict__ temp,
                      const float* __restrict__ rnq, const float* __restrict__ rnk,
                      u16* __restrict__ ptil) {
  int h = blockIdx.x, b = blockIdx.y, tid = threadIdx.x;
  int g = h >> 2;
  __shared__ float S[2304];
  size_t base = ((size_t)((b * 8 + h) * 64)) * 2304;
  for (int e = tid; e < 2304; e += 64) {
    float s = 0.f;
    for (int j = 0; j < 64; ++j) s += spart[base + (size_t)j * 2304 + e];
    S[e] = s;
  }
  __syncthreads();
  if (tid < 48) {
    int c = tid;
    float sq = temp[h] * rnq[b * 384 + h * 48 + c];
    float mx = -1e30f;
    for (int d = 0; d < 48; ++d) {
      float v = S[c * 48 + d] * sq * rnk[b * 96 + g * 48 + d];
      mx = fmaxf(mx, v);
    }
    float sum = 0.f;
    for (int d = 0; d < 48; ++d) {
      float v = S[c * 48 + d] * sq * rnk[b * 96 + g * 48 + d];
      sum += __expf(v - mx);
    }
    float inv = 1.f / sum;
    u16* row = ptil + ((size_t)(b * 384 + h * 48 + c)) * 96;
    for (int dk = 0; dk < 96; ++dk) {
      int d = dk - g * 48;
      float pv = 0.f;
      if (d >= 0 && d < 48) {
        float v = S[c * 48 + d] * sq * rnk[b * 96 + g * 48 + d];
        pv = __expf(v - mx) * inv;
      }
      row[dk] = f2b(pv);
    }
  }
}

// ---------------------------------------------------------------------------
// k8: Yt[p][c] = sum_dk vt[p][dk] * P~[c][dk].  grid (128, 8), 512 thr.
// ---------------------------------------------------------------------------
__global__ __launch_bounds__(512) void k8_pv(const u16* __restrict__ vt,
                                             const u16* __restrict__ ptil,
                                             u16* __restrict__ yt) {
  int ptb = blockIdx.x, b = blockIdx.y;
  int tid = threadIdx.x;
  int w = tid >> 6, l = tid & 63, lr = l & 15, lg = l >> 4;
  int wm = w >> 2, wn = w & 3;

  f32x4 acc[4][6] = {};
  size_t arow0 = ((size_t)(b * HW + ptb * 128 + wm * 64 + lr)) * 96;
  size_t brow0 = ((size_t)(b * CDIM + wn * 96 + lr)) * 96;

  for (int ks = 0; ks < 3; ++ks) {
    int ko = ks * 32 + lg * 8;
    s16x8 a[4], bb[6];
#pragma unroll
    for (int mf = 0; mf < 4; ++mf) a[mf] = *(const s16x8*)(vt + arow0 + (size_t)mf * 16 * 96 + ko);
#pragma unroll
    for (int nf = 0; nf < 6; ++nf) bb[nf] = *(const s16x8*)(ptil + brow0 + (size_t)nf * 16 * 96 + ko);
#pragma unroll
    for (int mf = 0; mf < 4; ++mf)
#pragma unroll
      for (int nf = 0; nf < 6; ++nf)
        acc[mf][nf] = __builtin_amdgcn_mfma_f32_16x16x32_bf16(a[mf], bb[nf], acc[mf][nf], 0, 0, 0);
  }

#pragma unroll
  for (int mf = 0; mf < 4; ++mf)
#pragma unroll
    for (int nf = 0; nf < 6; ++nf)
#pragma unroll
      for (int r = 0; r < 4; ++r) {
        int p = ptb * 128 + wm * 64 + mf * 16 + lg * 4 + r;
        int c = wn * 96 + nf * 16 + lr;
        yt[((size_t)(b * HW + p)) * 384 + c] = f2b(acc[mf][nf][r]);
      }
}

// ---------------------------------------------------------------------------
extern "C" void kernel_launch(void* const* d_in, const int* in_sizes, int n_in,
                              void* d_out, int out_size, void* d_ws, size_t ws_size,
                              hipStream_t stream) {
  const float* q    = (const float*)d_in[0];
  const float* k    = (const float*)d_in[1];
  const float* w_q  = (const float*)d_in[2];
  const float* w_kv = (const float*)d_in[3];
  const float* w_qd = (const float*)d_in[4];
  const float* w_kd = (const float*)d_in[5];
  const float* w_o  = (const float*)d_in[6];
  const float* temp = (const float*)d_in[7];
  const float* lnqw = (const float*)d_in[8];
  const float* lnqb = (const float*)d_in[9];
  const float* lnkw = (const float*)d_in[10];
  const float* lnkb = (const float*)d_in[11];
  float* out = (float*)d_out;

  char* ws = (char*)d_ws;
  size_t off = 0;
  auto alloc = [&](size_t bytes) -> void* {
    void* p = ws + off;
    off += (bytes + 255) & ~(size_t)255;
    return p;
  };

  u16*   wqp   = (u16*)alloc(384 * 384 * 2);
  float* rwsQ  = (float*)alloc(384 * 4);
  float* biasQ = (float*)alloc(384 * 4);
  u16*   wkvp  = (u16*)alloc(256 * 384 * 2);   // padded to 256 rows
  float* rwsKV = (float*)alloc(256 * 4);
  float* biasKV= (float*)alloc(256 * 4);
  u16*   wop   = (u16*)alloc(384 * 384 * 2);
  float* muQ   = (float*)alloc((size_t)NB * HW * 4);
  float* sdQ   = (float*)alloc((size_t)NB * HW * 4);
  float* muK   = (float*)alloc((size_t)NB * HW * 4);
  float* sdK   = (float*)alloc((size_t)NB * HW * 4);
  u16*   qt    = (u16*)alloc((size_t)NB * HW * CDIM * 2);  // aliased as qd later
  u16*   kt    = (u16*)alloc((size_t)NB * HW * CDIM * 2);  // aliased as kvd later
  u16*   qp    = (u16*)alloc((size_t)NB * CDIM * HW * 2);  // aliased as yt later
  u16*   kvp   = (u16*)alloc((size_t)NB * KVC * HW * 2);
  u16*   vt    = (u16*)alloc((size_t)NB * HW * 96 * 2);
  float* spart = (float*)alloc((size_t)4096 * 2304 * 4);
  u16*   ptil  = (u16*)alloc((size_t)NB * CDIM * 96 * 2);
  float* rnq   = (float*)alloc((size_t)NB * 384 * 4);
  float* rnk   = (float*)alloc((size_t)NB * 96 * 4);

  // lifetime aliases (sequential stream => safe)
  u16* qd  = qt;
  u16* kvd = kt;
  u16* yt  = qp;

  k0_prep<<<4, 256, 0, stream>>>(w_q, w_kv, w_o, lnqw, lnqb, lnkw, lnkb,
                                 wqp, rwsQ, biasQ, wkvp, rwsKV, biasKV, wop);

  k1_stats<<<dim3(64, NB, 2), 256, 0, stream>>>(q, k, qt, kt, muQ, sdQ, muK, sdK);

  gemm_bt<0><<<dim3(128, 3, NB), 256, 0, stream>>>(wqp, qt, rwsQ, biasQ, muQ, sdQ, qp, 384);
  gemm_bt<0><<<dim3(128, 2, NB), 256, 0, stream>>>(wkvp, kt, rwsKV, biasKV, muK, sdK, kvp, 192);

  k4_dw<<<dim3(576, NB), 256, 0, stream>>>(qp, kvp, w_qd, w_kd, qd, kvd, rnq, rnk);

  k5b_vt<<<dim3(64, NB), 256, 0, stream>>>(kvd, vt);

  k6_qk<<<dim3(16, 8, NB), 256, 0, stream>>>(qd, kvd, spart);
  k7_sm<<<dim3(8, NB), 64, 0, stream>>>(spart, temp, rnq, rnk, ptil);

  k8_pv<<<dim3(128, NB), 512, 0, stream>>>(vt, ptil, yt);

  gemm_bt<1><<<dim3(128, 3, NB), 256, 0, stream>>>(wop, yt, nullptr, nullptr, nullptr, nullptr, out, 384);
}

// Round 4
// 694.438 us; speedup vs baseline: 1.4850x; 1.4850x over previous
//
#include <hip/hip_runtime.h>
#include <math.h>

// ---------------------------------------------------------------------------
// CrossGroupedQueryAttention on MI355X — round 4
//
// R3 post-mortem: k1_stats write-fix broke reads (FETCH 722MB vs 402 ideal,
// 1.75x amp): transposed lane mapping -> 16B/line per wave, partial-line L2
// thrash. Root cause: NCHW f32 reads want lane=pixel, [p][c] writes want
// lane=channel. Resolution: DELETE k1_stats; fuse transpose+LN-stats into the
// projection GEMMs via LDS-staged B-tiles (read f32 coalesced, ds_write
// bf16 transposed, stride-36 pad = conflict-free-equivalent b64 frag reads).
// Out-projection stages yt (bf16) through the same path.
//
// Pipeline:
//  k0_prep       : fold LN gamma into w_q/w_kv (bf16), rowsums, biases, w_out->bf16
//  gemm_fused<0> : qp  = LN-GEMM(w_q',  LDS-staged q)  [b][384][hw] bf16
//  gemm_fused<0> : kvp = LN-GEMM(w_kv', LDS-staged k)  [b][192][hw] bf16
//  k4_dw         : depthwise 3x3 (LDS plane) -> qd, kvd + fused row l2norms
//  k5b_vt        : transpose v rows -> vt [b][p][96] bf16
//  k6_qk         : split-K QK^T partials
//  k7_sm         : reduce + scale + softmax -> P~ [b][384][96] bf16
//  k8_pv         : Yt[p][c] = vt x P~
//  gemm_fused<1> : out = w_out' x (LDS-staged Yt)  f32 NCHW
// ---------------------------------------------------------------------------

typedef unsigned short u16;
typedef unsigned int u32;
typedef short s16x8 __attribute__((ext_vector_type(8)));
typedef float f32x4 __attribute__((ext_vector_type(4)));

#define HW 16384
#define NB 8
#define CDIM 384
#define KVC 192

__device__ __forceinline__ float b2f(u16 u) {
  return __uint_as_float(((u32)u) << 16);
}
__device__ __forceinline__ u16 f2b(float f) {
  u32 u = __float_as_uint(f);
  u += 0x7fffu + ((u >> 16) & 1u);   // RNE
  return (u16)(u >> 16);
}

// ---------------------------------------------------------------------------
// k0: fold LN weights into conv weights.  1024 threads.
// ---------------------------------------------------------------------------
__global__ void k0_prep(const float* __restrict__ wq, const float* __restrict__ wkv,
                        const float* __restrict__ wo,
                        const float* __restrict__ lnqw, const float* __restrict__ lnqb,
                        const float* __restrict__ lnkw, const float* __restrict__ lnkb,
                        u16* __restrict__ wqp, float* __restrict__ rwsQ, float* __restrict__ biasQ,
                        u16* __restrict__ wkvp, float* __restrict__ rwsKV, float* __restrict__ biasKV,
                        u16* __restrict__ wop) {
  int r = blockIdx.x * 256 + threadIdx.x;
  if (r < 384) {
    float rs = 0.f, bs = 0.f;
    for (int i = 0; i < 384; ++i) {
      float wp = wq[r * 384 + i] * lnqw[i];
      u16 h = f2b(wp);
      rs += b2f(h);
      bs += wq[r * 384 + i] * lnqb[i];
      wqp[r * 384 + i] = h;
    }
    rwsQ[r] = rs; biasQ[r] = bs;
  } else if (r < 640) {
    int o = r - 384;
    if (o < 192) {
      float rs = 0.f, bs = 0.f;
      for (int i = 0; i < 384; ++i) {
        float wp = wkv[o * 384 + i] * lnkw[i];
        u16 h = f2b(wp);
        rs += b2f(h);
        bs += wkv[o * 384 + i] * lnkb[i];
        wkvp[o * 384 + i] = h;
      }
      rwsKV[o] = rs; biasKV[o] = bs;
    } else {
      for (int i = 0; i < 384; ++i) wkvp[o * 384 + i] = 0;
      rwsKV[o] = 0.f; biasKV[o] = 0.f;
    }
  } else {
    int o = r - 640;
    for (int i = 0; i < 384; ++i) wop[o * 384 + i] = f2b(wo[o * 384 + i]);
  }
}

// ---------------------------------------------------------------------------
// gemm_fused: D[o][p] = sum_k A[o][k]*B[p][k], K=384, tile 128o x 128p,
// 4 waves (2x2). B staged through LDS per 32-ch K-step.
// MODE 0: B from f32 NCHW (q/k); per-pixel LN stats computed during staging;
//         LN epilogue; bf16 out [b][M][hw].
// MODE 1: B from bf16 [p][384] (yt); plain f32 out [b][384][hw].
// LDS tile: 128 rows x 36 u16 (32 data + 4 pad) = 72B rows -> b64 frag reads
// land uniformly 4 accesses/bank (conflict-free-equivalent); writes <=4-way.
// ---------------------------------------------------------------------------
template <int MODE>
__global__ __launch_bounds__(256) void gemm_fused(const u16* __restrict__ A,
                                                  const void* __restrict__ Bsrc,
                                                  const float* __restrict__ rowsum,
                                                  const float* __restrict__ bias,
                                                  void* __restrict__ outv, int M) {
  __shared__ u16 tile[128 * 36];
  __shared__ float sumL[128], sqL[128], muL[128], sdL[128];

  const int b = blockIdx.z, ot = blockIdx.y, pt = blockIdx.x;
  const int tid = threadIdx.x;
  const int w = tid >> 6, l = tid & 63;
  const int wm = w >> 1, wn = w & 1, lr = l & 15, lg = l >> 4;

  f32x4 acc[4][4] = {};
  const int arow0 = ot * 128 + wm * 64 + lr;

  // staging mappings
  const int px0 = (tid & 15) + ((tid >> 4) & 7) * 16;  // MODE 0: 0..127 bijective
  const int cslot = tid >> 7;                           // MODE 0: 0/1
  const int px1 = tid >> 2;                             // MODE 1: 0..63 (and +64)
  const int q4 = tid & 3;                               // MODE 1: uint4 slot

  const float* Bf = (const float*)Bsrc;
  const u16* Bh = (const u16*)Bsrc;
  const size_t fbase = (size_t)b * CDIM * HW + pt * 128 + px0;   // MODE 0
  const size_t ybase0 = ((size_t)(b * HW + pt * 128 + px1)) * 384 + q4 * 8;       // MODE 1
  const size_t ybase1 = ((size_t)(b * HW + pt * 128 + px1 + 64)) * 384 + q4 * 8;

  float sum = 0.f, sq = 0.f;
  float pv[16];
  uint4 yv0, yv1;

  // ---- prefetch k-step 0
  if (MODE == 0) {
#pragma unroll
    for (int e = 0; e < 16; ++e)
      pv[e] = Bf[fbase + (size_t)(cslot * 16 + e) * HW];
  } else {
    yv0 = *(const uint4*)(Bh + ybase0);
    yv1 = *(const uint4*)(Bh + ybase1);
  }

  for (int ks = 0; ks < 12; ++ks) {
    // ---- store staged regs to LDS (+ stats for MODE 0)
    if (MODE == 0) {
      u32* t32 = (u32*)tile;
#pragma unroll
      for (int e = 0; e < 16; e += 2) {
        float v0 = pv[e], v1 = pv[e + 1];
        sum += v0 + v1;
        sq += v0 * v0 + v1 * v1;
        t32[px0 * 18 + cslot * 8 + (e >> 1)] = (u32)f2b(v0) | ((u32)f2b(v1) << 16);
      }
    } else {
      uint2* t64 = (uint2*)tile;
      t64[px1 * 9 + q4 * 2]            = make_uint2(yv0.x, yv0.y);
      t64[px1 * 9 + q4 * 2 + 1]        = make_uint2(yv0.z, yv0.w);
      t64[(px1 + 64) * 9 + q4 * 2]     = make_uint2(yv1.x, yv1.y);
      t64[(px1 + 64) * 9 + q4 * 2 + 1] = make_uint2(yv1.z, yv1.w);
    }
    __syncthreads();

    // ---- prefetch next k-step while MFMA consumes current tile
    if (ks < 11) {
      if (MODE == 0) {
#pragma unroll
        for (int e = 0; e < 16; ++e)
          pv[e] = Bf[fbase + (size_t)((ks + 1) * 32 + cslot * 16 + e) * HW];
      } else {
        yv0 = *(const uint4*)(Bh + ybase0 + (ks + 1) * 32);
        yv1 = *(const uint4*)(Bh + ybase1 + (ks + 1) * 32);
      }
    }

    // ---- MFMA on current tile
    const int ko = ks * 32 + lg * 8;
    s16x8 a[4];
#pragma unroll
    for (int mf = 0; mf < 4; ++mf)
      a[mf] = *(const s16x8*)(A + (size_t)(arow0 + mf * 16) * 384 + ko);

    s16x8 bb[4];
    const uint2* t2 = (const uint2*)tile;
#pragma unroll
    for (int nf = 0; nf < 4; ++nf) {
      int row = wn * 64 + nf * 16 + lr;
      union { uint2 u2[2]; s16x8 v; } tmp;
      tmp.u2[0] = t2[row * 9 + lg * 2];
      tmp.u2[1] = t2[row * 9 + lg * 2 + 1];
      bb[nf] = tmp.v;
    }
#pragma unroll
    for (int mf = 0; mf < 4; ++mf)
#pragma unroll
      for (int nf = 0; nf < 4; ++nf)
        acc[mf][nf] = __builtin_amdgcn_mfma_f32_16x16x32_bf16(a[mf], bb[nf], acc[mf][nf], 0, 0, 0);
    __syncthreads();
  }

  // ---- LN stats combine (MODE 0): block covers all 384 channels of its 128 px
  if (MODE == 0) {
    if (cslot == 0) { sumL[px0] = sum; sqL[px0] = sq; }
    __syncthreads();
    if (cslot == 1) {
      float s = sumL[px0] + sum, q2 = sqL[px0] + sq;
      float mn = s * (1.f / 384.f);
      float var = q2 * (1.f / 384.f) - mn * mn;
      muL[px0] = mn;
      sdL[px0] = rsqrtf(var + 1e-5f);
    }
    __syncthreads();
  }

  // ---- epilogue
#pragma unroll
  for (int nf = 0; nf < 4; ++nf) {
    int row = wn * 64 + nf * 16 + lr;
    int p = pt * 128 + row;
    float m_ = 0.f, s_ = 0.f;
    if (MODE == 0) { m_ = muL[row]; s_ = sdL[row]; }
#pragma unroll
    for (int mf = 0; mf < 4; ++mf) {
#pragma unroll
      for (int r = 0; r < 4; ++r) {
        int o = ot * 128 + wm * 64 + mf * 16 + lg * 4 + r;
        if (MODE == 0) {
          if (o < M) {
            float v = s_ * (acc[mf][nf][r] - m_ * rowsum[o]) + bias[o];
            ((u16*)outv)[((size_t)(b * M + o)) * HW + p] = f2b(v);
          }
        } else {
          ((float*)outv)[((size_t)(b * CDIM + o)) * HW + p] = acc[mf][nf][r];
        }
      }
    }
  }
}

// ---------------------------------------------------------------------------
// k4: depthwise 3x3 (zero pad), LDS-staged plane + fused row l2-norm.
// ---------------------------------------------------------------------------
__global__ __launch_bounds__(256) void k4_dw(const u16* __restrict__ qp, const u16* __restrict__ kvp,
                                             const float* __restrict__ wqdw, const float* __restrict__ wkvdw,
                                             u16* __restrict__ qd, u16* __restrict__ kvd,
                                             float* __restrict__ rnq, float* __restrict__ rnk) {
  __shared__ u16 plane[16384];     // 32 KB
  __shared__ float red[256];

  int c = blockIdx.x, b = blockIdx.y;
  int tid = threadIdx.x;
  const u16* in; u16* outb; const float* wp; int C;
  int isQ = (c < 384), cc = isQ ? c : c - 384;
  if (isQ) { in = qp; outb = qd; wp = wqdw + cc * 9; C = CDIM; }
  else     { in = kvp; outb = kvd; wp = wkvdw + cc * 9; C = KVC; }
  size_t base = ((size_t)(b * C + cc)) * HW;

  float w[9];
#pragma unroll
  for (int j = 0; j < 9; ++j) w[j] = wp[j];

  const uint4* gsrc = (const uint4*)(in + base);
  uint4* lplane = (uint4*)plane;
#pragma unroll
  for (int i = 0; i < 8; ++i) lplane[tid + i * 256] = gsrc[tid + i * 256];
  __syncthreads();

  uint4* gdst = (uint4*)(outb + base);
  float ns = 0.f;
#pragma unroll
  for (int it = 0; it < 8; ++it) {
    int idx = tid + it * 256;
    int y = idx >> 4, ox = idx & 15;
    int x0 = ox * 8;

    float r[3][10];
#pragma unroll
    for (int rr = 0; rr < 3; ++rr) {
      int yy = y + rr - 1;
      if ((unsigned)yy < 128u) {
        int rbase = yy * 128 + x0;
        r[rr][0] = (x0 > 0) ? b2f(plane[rbase - 1]) : 0.f;
        uint4 v = *(const uint4*)&plane[rbase];
        u32 ws[4] = {v.x, v.y, v.z, v.w};
#pragma unroll
        for (int j = 0; j < 4; ++j) {
          r[rr][1 + 2 * j] = b2f((u16)(ws[j] & 0xffff));
          r[rr][2 + 2 * j] = b2f((u16)(ws[j] >> 16));
        }
        r[rr][9] = (x0 < 120) ? b2f(plane[rbase + 8]) : 0.f;
      } else {
#pragma unroll
        for (int j = 0; j < 10; ++j) r[rr][j] = 0.f;
      }
    }

    u32 packed[4];
#pragma unroll
    for (int j = 0; j < 8; ++j) {
      float a = 0.f;
#pragma unroll
      for (int rr = 0; rr < 3; ++rr)
#pragma unroll
        for (int dx = 0; dx < 3; ++dx)
          a += w[rr * 3 + dx] * r[rr][j + dx];
      u16 h = f2b(a);
      float hv = b2f(h);
      ns += hv * hv;
      if (j & 1) packed[j >> 1] |= ((u32)h) << 16; else packed[j >> 1] = (u32)h;
    }
    gdst[idx] = make_uint4(packed[0], packed[1], packed[2], packed[3]);
  }

  red[tid] = ns;
  __syncthreads();
  for (int st = 128; st > 0; st >>= 1) {
    if (tid < st) red[tid] += red[tid + st];
    __syncthreads();
  }
  if (tid == 0) {
    float n = sqrtf(red[0]);
    float inv = 1.f / fmaxf(n, 1e-12f);
    if (isQ) rnq[b * 384 + cc] = inv;
    else if (cc < 96) rnk[b * 96 + cc] = inv;
  }
}

// ---------------------------------------------------------------------------
// k5b: transpose v (kvd rows 96..191) -> vt [b][p][96] bf16. grid (64, 8).
// ---------------------------------------------------------------------------
__global__ void k5b_vt(const u16* __restrict__ kvd, u16* __restrict__ vt) {
  int p = blockIdx.x * 256 + threadIdx.x;
  int b = blockIdx.y;
  size_t sb = ((size_t)(b * KVC + 96)) * HW + p;
  uint4* dv = (uint4*)vt + ((size_t)(b * HW + p)) * 12;
  for (int j8 = 0; j8 < 12; ++j8) {
    u32 w[4];
#pragma unroll
    for (int j = 0; j < 8; ++j) {
      u16 h = kvd[sb + (size_t)(j8 * 8 + j) * HW];
      if (j & 1) w[j >> 1] |= ((u32)h) << 16; else w[j >> 1] = (u32)h;
    }
    dv[j8] = make_uint4(w[0], w[1], w[2], w[3]);
  }
}

// ---------------------------------------------------------------------------
// k6: split-K QK^T partials. grid (16, 8, 8).
// ---------------------------------------------------------------------------
__global__ __launch_bounds__(256) void k6_qk(const u16* __restrict__ qd,
                                             const u16* __restrict__ kvd,
                                             float* __restrict__ spart) {
  int kc = blockIdx.x, h = blockIdx.y, b = blockIdx.z;
  int tid = threadIdx.x;
  int w = tid >> 6, l = tid & 63, lr = l & 15, lg = l >> 4;
  int g = h >> 2;
  int p0 = kc * 1024 + w * 256;

  f32x4 acc[3][3] = {};
  size_t qbase = ((size_t)(b * CDIM + h * 48 + lr)) * HW;
  size_t kbase = ((size_t)(b * KVC + g * 48 + lr)) * HW;

  for (int ks = 0; ks < 8; ++ks) {
    int pp = p0 + ks * 32 + lg * 8;
    s16x8 a[3], bb[3];
#pragma unroll
    for (int mi = 0; mi < 3; ++mi) a[mi] = *(const s16x8*)(qd + qbase + (size_t)mi * 16 * HW + pp);
#pragma unroll
    for (int ni = 0; ni < 3; ++ni) bb[ni] = *(const s16x8*)(kvd + kbase + (size_t)ni * 16 * HW + pp);
#pragma unroll
    for (int mi = 0; mi < 3; ++mi)
#pragma unroll
      for (int ni = 0; ni < 3; ++ni)
        acc[mi][ni] = __builtin_amdgcn_mfma_f32_16x16x32_bf16(a[mi], bb[ni], acc[mi][ni], 0, 0, 0);
  }

  size_t sb = ((size_t)((((b * 8 + h) * 16) + kc) * 4 + w)) * 2304;
#pragma unroll
  for (int mi = 0; mi < 3; ++mi)
#pragma unroll
    for (int ni = 0; ni < 3; ++ni)
#pragma unroll
      for (int r = 0; r < 4; ++r) {
        int c = mi * 16 + lg * 4 + r, d = ni * 16 + lr;
        spart[sb + c * 48 + d] = acc[mi][ni][r];
      }
}

// ---------------------------------------------------------------------------
// k7: reduce partials + scale + softmax -> P~ [b][384][96] bf16.
// ---------------------------------------------------------------------------
__global__ void k7_sm(const float* __restrict__ spart, const float* __restrict__ temp,
                      const float* __restrict__ rnq, const float* __restrict__ rnk,
                      u16* __restrict__ ptil) {
  int h = blockIdx.x, b = blockIdx.y, tid = threadIdx.x;
  int g = h >> 2;
  __shared__ float S[2304];
  size_t base = ((size_t)((b * 8 + h) * 64)) * 2304;
  for (int e = tid; e < 2304; e += 64) {
    float s = 0.f;
    for (int j = 0; j < 64; ++j) s += spart[base + (size_t)j * 2304 + e];
    S[e] = s;
  }
  __syncthreads();
  if (tid < 48) {
    int c = tid;
    float sq = temp[h] * rnq[b * 384 + h * 48 + c];
    float mx = -1e30f;
    for (int d = 0; d < 48; ++d) {
      float v = S[c * 48 + d] * sq * rnk[b * 96 + g * 48 + d];
      mx = fmaxf(mx, v);
    }
    float sum = 0.f;
    for (int d = 0; d < 48; ++d) {
      float v = S[c * 48 + d] * sq * rnk[b * 96 + g * 48 + d];
      sum += __expf(v - mx);
    }
    float inv = 1.f / sum;
    u16* row = ptil + ((size_t)(b * 384 + h * 48 + c)) * 96;
    for (int dk = 0; dk < 96; ++dk) {
      int d = dk - g * 48;
      float pv = 0.f;
      if (d >= 0 && d < 48) {
        float v = S[c * 48 + d] * sq * rnk[b * 96 + g * 48 + d];
        pv = __expf(v - mx) * inv;
      }
      row[dk] = f2b(pv);
    }
  }
}

// ---------------------------------------------------------------------------
// k8: Yt[p][c] = sum_dk vt[p][dk] * P~[c][dk].  grid (128, 8), 512 thr.
// ---------------------------------------------------------------------------
__global__ __launch_bounds__(512) void k8_pv(const u16* __restrict__ vt,
                                             const u16* __restrict__ ptil,
                                             u16* __restrict__ yt) {
  int ptb = blockIdx.x, b = blockIdx.y;
  int tid = threadIdx.x;
  int w = tid >> 6, l = tid & 63, lr = l & 15, lg = l >> 4;
  int wm = w >> 2, wn = w & 3;

  f32x4 acc[4][6] = {};
  size_t arow0 = ((size_t)(b * HW + ptb * 128 + wm * 64 + lr)) * 96;
  size_t brow0 = ((size_t)(b * CDIM + wn * 96 + lr)) * 96;

  for (int ks = 0; ks < 3; ++ks) {
    int ko = ks * 32 + lg * 8;
    s16x8 a[4], bb[6];
#pragma unroll
    for (int mf = 0; mf < 4; ++mf) a[mf] = *(const s16x8*)(vt + arow0 + (size_t)mf * 16 * 96 + ko);
#pragma unroll
    for (int nf = 0; nf < 6; ++nf) bb[nf] = *(const s16x8*)(ptil + brow0 + (size_t)nf * 16 * 96 + ko);
#pragma unroll
    for (int mf = 0; mf < 4; ++mf)
#pragma unroll
      for (int nf = 0; nf < 6; ++nf)
        acc[mf][nf] = __builtin_amdgcn_mfma_f32_16x16x32_bf16(a[mf], bb[nf], acc[mf][nf], 0, 0, 0);
  }

#pragma unroll
  for (int mf = 0; mf < 4; ++mf)
#pragma unroll
    for (int nf = 0; nf < 6; ++nf)
#pragma unroll
      for (int r = 0; r < 4; ++r) {
        int p = ptb * 128 + wm * 64 + mf * 16 + lg * 4 + r;
        int c = wn * 96 + nf * 16 + lr;
        yt[((size_t)(b * HW + p)) * 384 + c] = f2b(acc[mf][nf][r]);
      }
}

// ---------------------------------------------------------------------------
extern "C" void kernel_launch(void* const* d_in, const int* in_sizes, int n_in,
                              void* d_out, int out_size, void* d_ws, size_t ws_size,
                              hipStream_t stream) {
  const float* q    = (const float*)d_in[0];
  const float* k    = (const float*)d_in[1];
  const float* w_q  = (const float*)d_in[2];
  const float* w_kv = (const float*)d_in[3];
  const float* w_qd = (const float*)d_in[4];
  const float* w_kd = (const float*)d_in[5];
  const float* w_o  = (const float*)d_in[6];
  const float* temp = (const float*)d_in[7];
  const float* lnqw = (const float*)d_in[8];
  const float* lnqb = (const float*)d_in[9];
  const float* lnkw = (const float*)d_in[10];
  const float* lnkb = (const float*)d_in[11];
  float* out = (float*)d_out;

  char* ws = (char*)d_ws;
  size_t off = 0;
  auto alloc = [&](size_t bytes) -> void* {
    void* p = ws + off;
    off += (bytes + 255) & ~(size_t)255;
    return p;
  };

  u16*   wqp   = (u16*)alloc(384 * 384 * 2);
  float* rwsQ  = (float*)alloc(384 * 4);
  float* biasQ = (float*)alloc(384 * 4);
  u16*   wkvp  = (u16*)alloc(256 * 384 * 2);   // padded to 256 rows
  float* rwsKV = (float*)alloc(256 * 4);
  float* biasKV= (float*)alloc(256 * 4);
  u16*   wop   = (u16*)alloc(384 * 384 * 2);
  u16*   qp    = (u16*)alloc((size_t)NB * CDIM * HW * 2);  // aliased as yt later
  u16*   kvp   = (u16*)alloc((size_t)NB * KVC * HW * 2);
  u16*   qd    = (u16*)alloc((size_t)NB * CDIM * HW * 2);
  u16*   kvd   = (u16*)alloc((size_t)NB * KVC * HW * 2);
  u16*   vt    = (u16*)alloc((size_t)NB * HW * 96 * 2);
  float* spart = (float*)alloc((size_t)4096 * 2304 * 4);
  u16*   ptil  = (u16*)alloc((size_t)NB * CDIM * 96 * 2);
  float* rnq   = (float*)alloc((size_t)NB * 384 * 4);
  float* rnk   = (float*)alloc((size_t)NB * 96 * 4);

  // lifetime alias (sequential stream => safe): qp dead after k4
  u16* yt = qp;

  k0_prep<<<4, 256, 0, stream>>>(w_q, w_kv, w_o, lnqw, lnqb, lnkw, lnkb,
                                 wqp, rwsQ, biasQ, wkvp, rwsKV, biasKV, wop);

  gemm_fused<0><<<dim3(128, 3, NB), 256, 0, stream>>>(wqp, q, rwsQ, biasQ, qp, 384);
  gemm_fused<0><<<dim3(128, 2, NB), 256, 0, stream>>>(wkvp, k, rwsKV, biasKV, kvp, 192);

  k4_dw<<<dim3(576, NB), 256, 0, stream>>>(qp, kvp, w_qd, w_kd, qd, kvd, rnq, rnk);

  k5b_vt<<<dim3(64, NB), 256, 0, stream>>>(kvd, vt);

  k6_qk<<<dim3(16, 8, NB), 256, 0, stream>>>(qd, kvd, spart);
  k7_sm<<<dim3(8, NB), 64, 0, stream>>>(spart, temp, rnq, rnk, ptil);

  k8_pv<<<dim3(128, NB), 512, 0, stream>>>(vt, ptil, yt);

  gemm_fused<1><<<dim3(128, 3, NB), 256, 0, stream>>>(wop, yt, nullptr, nullptr, out, 384);
}

// Round 5
// 681.764 us; speedup vs baseline: 1.5126x; 1.0186x over previous
//
#include <hip/hip_runtime.h>
#include <math.h>

// ---------------------------------------------------------------------------
// CrossGroupedQueryAttention on MI355X — round 5
//
// R4 post-mortem: all three gemm_fused dispatches latency/barrier-bound
// (MfmaUtil 7.4%, VALU 25%, HBM 17%, occ 21% — nothing saturated; 4x over
// the 48us memory floor). Fix: 1-barrier double-buffered K-loop (write
// tile[cur^1] while MFMA reads tile[cur]; single syncthreads both publishes
// the new tile and protects the old), A-frags issued at top of iteration,
// B-prefetch one step ahead, ds_write_b64 staging stores.
// ---------------------------------------------------------------------------

typedef unsigned short u16;
typedef unsigned int u32;
typedef short s16x8 __attribute__((ext_vector_type(8)));
typedef float f32x4 __attribute__((ext_vector_type(4)));

#define HW 16384
#define NB 8
#define CDIM 384
#define KVC 192

__device__ __forceinline__ float b2f(u16 u) {
  return __uint_as_float(((u32)u) << 16);
}
__device__ __forceinline__ u16 f2b(float f) {
  u32 u = __float_as_uint(f);
  u += 0x7fffu + ((u >> 16) & 1u);   // RNE
  return (u16)(u >> 16);
}

// ---------------------------------------------------------------------------
// k0: fold LN weights into conv weights.  1024 threads.
// ---------------------------------------------------------------------------
__global__ void k0_prep(const float* __restrict__ wq, const float* __restrict__ wkv,
                        const float* __restrict__ wo,
                        const float* __restrict__ lnqw, const float* __restrict__ lnqb,
                        const float* __restrict__ lnkw, const float* __restrict__ lnkb,
                        u16* __restrict__ wqp, float* __restrict__ rwsQ, float* __restrict__ biasQ,
                        u16* __restrict__ wkvp, float* __restrict__ rwsKV, float* __restrict__ biasKV,
                        u16* __restrict__ wop) {
  int r = blockIdx.x * 256 + threadIdx.x;
  if (r < 384) {
    float rs = 0.f, bs = 0.f;
    for (int i = 0; i < 384; ++i) {
      float wp = wq[r * 384 + i] * lnqw[i];
      u16 h = f2b(wp);
      rs += b2f(h);
      bs += wq[r * 384 + i] * lnqb[i];
      wqp[r * 384 + i] = h;
    }
    rwsQ[r] = rs; biasQ[r] = bs;
  } else if (r < 640) {
    int o = r - 384;
    if (o < 192) {
      float rs = 0.f, bs = 0.f;
      for (int i = 0; i < 384; ++i) {
        float wp = wkv[o * 384 + i] * lnkw[i];
        u16 h = f2b(wp);
        rs += b2f(h);
        bs += wkv[o * 384 + i] * lnkb[i];
        wkvp[o * 384 + i] = h;
      }
      rwsKV[o] = rs; biasKV[o] = bs;
    } else {
      for (int i = 0; i < 384; ++i) wkvp[o * 384 + i] = 0;
      rwsKV[o] = 0.f; biasKV[o] = 0.f;
    }
  } else {
    int o = r - 640;
    for (int i = 0; i < 384; ++i) wop[o * 384 + i] = f2b(wo[o * 384 + i]);
  }
}

// ---------------------------------------------------------------------------
// gemm_fused: D[o][p] = sum_k A[o][k]*B[p][k], K=384, tile 128o x 128p,
// 4 waves (2x2). B double-buffered through LDS per 32-ch K-step, 1 barrier.
// MODE 0: B from f32 NCHW (q/k); LN stats during staging; LN epilogue; bf16 out.
// MODE 1: B from bf16 [p][384] (yt); plain f32 out NCHW.
// LDS rows 36 u16 (72B): b64 accesses spread across banks (<=4-way).
// ---------------------------------------------------------------------------
template <int MODE>
__global__ __launch_bounds__(256) void gemm_fused(const u16* __restrict__ A,
                                                  const void* __restrict__ Bsrc,
                                                  const float* __restrict__ rowsum,
                                                  const float* __restrict__ bias,
                                                  void* __restrict__ outv, int M) {
  __shared__ u16 tile[2][128 * 36];
  __shared__ float sumL[128], sqL[128], muL[128], sdL[128];

  const int b = blockIdx.z, ot = blockIdx.y, pt = blockIdx.x;
  const int tid = threadIdx.x;
  const int w = tid >> 6, l = tid & 63;
  const int wm = w >> 1, wn = w & 1, lr = l & 15, lg = l >> 4;

  f32x4 acc[4][4] = {};
  const int arow0 = ot * 128 + wm * 64 + lr;

  // staging mappings
  const int px0 = (tid & 15) + ((tid >> 4) & 7) * 16;  // MODE 0: 0..127 bijective
  const int cslot = tid >> 7;                           // MODE 0: 0/1
  const int px1 = tid >> 2;                             // MODE 1: 0..63 (and +64)
  const int q4 = tid & 3;                               // MODE 1: uint4 slot

  const float* Bf = (const float*)Bsrc;
  const u16* Bh = (const u16*)Bsrc;
  const size_t fbase = (size_t)b * CDIM * HW + pt * 128 + px0;   // MODE 0
  const size_t ybase0 = ((size_t)(b * HW + pt * 128 + px1)) * 384 + q4 * 8;       // MODE 1
  const size_t ybase1 = ((size_t)(b * HW + pt * 128 + px1 + 64)) * 384 + q4 * 8;

  float pv[16];
  uint4 yv0, yv1;
  float sum = 0.f, sq = 0.f;

  auto loadB = [&](int ks) {
    if (MODE == 0) {
#pragma unroll
      for (int e = 0; e < 16; ++e)
        pv[e] = Bf[fbase + (size_t)(ks * 32 + cslot * 16 + e) * HW];
    } else {
      yv0 = *(const uint4*)(Bh + ybase0 + ks * 32);
      yv1 = *(const uint4*)(Bh + ybase1 + ks * 32);
    }
  };
  auto storeB = [&](int buf) {
    uint2* t64 = (uint2*)(tile[buf]);
    if (MODE == 0) {
#pragma unroll
      for (int e = 0; e < 16; e += 4) {
        float v0 = pv[e], v1 = pv[e + 1], v2 = pv[e + 2], v3 = pv[e + 3];
        sum += (v0 + v1) + (v2 + v3);
        sq += (v0 * v0 + v1 * v1) + (v2 * v2 + v3 * v3);
        u32 lo = (u32)f2b(v0) | ((u32)f2b(v1) << 16);
        u32 hi = (u32)f2b(v2) | ((u32)f2b(v3) << 16);
        t64[px0 * 9 + cslot * 4 + (e >> 2)] = make_uint2(lo, hi);
      }
    } else {
      t64[px1 * 9 + q4 * 2]            = make_uint2(yv0.x, yv0.y);
      t64[px1 * 9 + q4 * 2 + 1]        = make_uint2(yv0.z, yv0.w);
      t64[(px1 + 64) * 9 + q4 * 2]     = make_uint2(yv1.x, yv1.y);
      t64[(px1 + 64) * 9 + q4 * 2 + 1] = make_uint2(yv1.z, yv1.w);
    }
  };

  // prologue: stage k-step 0 into buf 0
  loadB(0);
  storeB(0);
  __syncthreads();

  int cur = 0;
  for (int ks = 0; ks < 12; ++ks) {
    // A-frags for current k-step (issued first; L2-resident)
    const int ko = ks * 32 + lg * 8;
    s16x8 a[4];
#pragma unroll
    for (int mf = 0; mf < 4; ++mf)
      a[mf] = *(const s16x8*)(A + (size_t)(arow0 + mf * 16) * 384 + ko);

    // prefetch next B tile into registers (HBM latency spans MFMA phase)
    if (ks < 11) loadB(ks + 1);

    // B-frags from tile[cur]
    s16x8 bb[4];
    const uint2* t2 = (const uint2*)(tile[cur]);
#pragma unroll
    for (int nf = 0; nf < 4; ++nf) {
      int row = wn * 64 + nf * 16 + lr;
      union { uint2 u2[2]; s16x8 v; } tmp;
      tmp.u2[0] = t2[row * 9 + lg * 2];
      tmp.u2[1] = t2[row * 9 + lg * 2 + 1];
      bb[nf] = tmp.v;
    }
#pragma unroll
    for (int mf = 0; mf < 4; ++mf)
#pragma unroll
      for (int nf = 0; nf < 4; ++nf)
        acc[mf][nf] = __builtin_amdgcn_mfma_f32_16x16x32_bf16(a[mf], bb[nf], acc[mf][nf], 0, 0, 0);

    // store staged regs into the OTHER buffer (no conflict with reads of cur)
    if (ks < 11) storeB(cur ^ 1);
    __syncthreads();   // publishes cur^1, protects cur from next overwrite
    cur ^= 1;
  }

  // ---- LN stats combine (MODE 0): block covers all 384 channels of its 128 px
  if (MODE == 0) {
    if (cslot == 0) { sumL[px0] = sum; sqL[px0] = sq; }
    __syncthreads();
    if (cslot == 1) {
      float s = sumL[px0] + sum, q2 = sqL[px0] + sq;
      float mn = s * (1.f / 384.f);
      float var = q2 * (1.f / 384.f) - mn * mn;
      muL[px0] = mn;
      sdL[px0] = rsqrtf(var + 1e-5f);
    }
    __syncthreads();
  }

  // ---- epilogue
#pragma unroll
  for (int nf = 0; nf < 4; ++nf) {
    int row = wn * 64 + nf * 16 + lr;
    int p = pt * 128 + row;
    float m_ = 0.f, s_ = 0.f;
    if (MODE == 0) { m_ = muL[row]; s_ = sdL[row]; }
#pragma unroll
    for (int mf = 0; mf < 4; ++mf) {
#pragma unroll
      for (int r = 0; r < 4; ++r) {
        int o = ot * 128 + wm * 64 + mf * 16 + lg * 4 + r;
        if (MODE == 0) {
          if (o < M) {
            float v = s_ * (acc[mf][nf][r] - m_ * rowsum[o]) + bias[o];
            ((u16*)outv)[((size_t)(b * M + o)) * HW + p] = f2b(v);
          }
        } else {
          ((float*)outv)[((size_t)(b * CDIM + o)) * HW + p] = acc[mf][nf][r];
        }
      }
    }
  }
}

// ---------------------------------------------------------------------------
// k4: depthwise 3x3 (zero pad), LDS-staged plane + fused row l2-norm.
// ---------------------------------------------------------------------------
__global__ __launch_bounds__(256) void k4_dw(const u16* __restrict__ qp, const u16* __restrict__ kvp,
                                             const float* __restrict__ wqdw, const float* __restrict__ wkvdw,
                                             u16* __restrict__ qd, u16* __restrict__ kvd,
                                             float* __restrict__ rnq, float* __restrict__ rnk) {
  __shared__ u16 plane[16384];     // 32 KB
  __shared__ float red[256];

  int c = blockIdx.x, b = blockIdx.y;
  int tid = threadIdx.x;
  const u16* in; u16* outb; const float* wp; int C;
  int isQ = (c < 384), cc = isQ ? c : c - 384;
  if (isQ) { in = qp; outb = qd; wp = wqdw + cc * 9; C = CDIM; }
  else     { in = kvp; outb = kvd; wp = wkvdw + cc * 9; C = KVC; }
  size_t base = ((size_t)(b * C + cc)) * HW;

  float w[9];
#pragma unroll
  for (int j = 0; j < 9; ++j) w[j] = wp[j];

  const uint4* gsrc = (const uint4*)(in + base);
  uint4* lplane = (uint4*)plane;
#pragma unroll
  for (int i = 0; i < 8; ++i) lplane[tid + i * 256] = gsrc[tid + i * 256];
  __syncthreads();

  uint4* gdst = (uint4*)(outb + base);
  float ns = 0.f;
#pragma unroll
  for (int it = 0; it < 8; ++it) {
    int idx = tid + it * 256;
    int y = idx >> 4, ox = idx & 15;
    int x0 = ox * 8;

    float r[3][10];
#pragma unroll
    for (int rr = 0; rr < 3; ++rr) {
      int yy = y + rr - 1;
      if ((unsigned)yy < 128u) {
        int rbase = yy * 128 + x0;
        r[rr][0] = (x0 > 0) ? b2f(plane[rbase - 1]) : 0.f;
        uint4 v = *(const uint4*)&plane[rbase];
        u32 ws[4] = {v.x, v.y, v.z, v.w};
#pragma unroll
        for (int j = 0; j < 4; ++j) {
          r[rr][1 + 2 * j] = b2f((u16)(ws[j] & 0xffff));
          r[rr][2 + 2 * j] = b2f((u16)(ws[j] >> 16));
        }
        r[rr][9] = (x0 < 120) ? b2f(plane[rbase + 8]) : 0.f;
      } else {
#pragma unroll
        for (int j = 0; j < 10; ++j) r[rr][j] = 0.f;
      }
    }

    u32 packed[4];
#pragma unroll
    for (int j = 0; j < 8; ++j) {
      float a = 0.f;
#pragma unroll
      for (int rr = 0; rr < 3; ++rr)
#pragma unroll
        for (int dx = 0; dx < 3; ++dx)
          a += w[rr * 3 + dx] * r[rr][j + dx];
      u16 h = f2b(a);
      float hv = b2f(h);
      ns += hv * hv;
      if (j & 1) packed[j >> 1] |= ((u32)h) << 16; else packed[j >> 1] = (u32)h;
    }
    gdst[idx] = make_uint4(packed[0], packed[1], packed[2], packed[3]);
  }

  red[tid] = ns;
  __syncthreads();
  for (int st = 128; st > 0; st >>= 1) {
    if (tid < st) red[tid] += red[tid + st];
    __syncthreads();
  }
  if (tid == 0) {
    float n = sqrtf(red[0]);
    float inv = 1.f / fmaxf(n, 1e-12f);
    if (isQ) rnq[b * 384 + cc] = inv;
    else if (cc < 96) rnk[b * 96 + cc] = inv;
  }
}

// ---------------------------------------------------------------------------
// k5b: transpose v (kvd rows 96..191) -> vt [b][p][96] bf16. grid (64, 8).
// ---------------------------------------------------------------------------
__global__ void k5b_vt(const u16* __restrict__ kvd, u16* __restrict__ vt) {
  int p = blockIdx.x * 256 + threadIdx.x;
  int b = blockIdx.y;
  size_t sb = ((size_t)(b * KVC + 96)) * HW + p;
  uint4* dv = (uint4*)vt + ((size_t)(b * HW + p)) * 12;
  for (int j8 = 0; j8 < 12; ++j8) {
    u32 w[4];
#pragma unroll
    for (int j = 0; j < 8; ++j) {
      u16 h = kvd[sb + (size_t)(j8 * 8 + j) * HW];
      if (j & 1) w[j >> 1] |= ((u32)h) << 16; else w[j >> 1] = (u32)h;
    }
    dv[j8] = make_uint4(w[0], w[1], w[2], w[3]);
  }
}

// ---------------------------------------------------------------------------
// k6: split-K QK^T partials. grid (16, 8, 8).
// ---------------------------------------------------------------------------
__global__ __launch_bounds__(256) void k6_qk(const u16* __restrict__ qd,
                                             const u16* __restrict__ kvd,
                                             float* __restrict__ spart) {
  int kc = blockIdx.x, h = blockIdx.y, b = blockIdx.z;
  int tid = threadIdx.x;
  int w = tid >> 6, l = tid & 63, lr = l & 15, lg = l >> 4;
  int g = h >> 2;
  int p0 = kc * 1024 + w * 256;

  f32x4 acc[3][3] = {};
  size_t qbase = ((size_t)(b * CDIM + h * 48 + lr)) * HW;
  size_t kbase = ((size_t)(b * KVC + g * 48 + lr)) * HW;

  for (int ks = 0; ks < 8; ++ks) {
    int pp = p0 + ks * 32 + lg * 8;
    s16x8 a[3], bb[3];
#pragma unroll
    for (int mi = 0; mi < 3; ++mi) a[mi] = *(const s16x8*)(qd + qbase + (size_t)mi * 16 * HW + pp);
#pragma unroll
    for (int ni = 0; ni < 3; ++ni) bb[ni] = *(const s16x8*)(kvd + kbase + (size_t)ni * 16 * HW + pp);
#pragma unroll
    for (int mi = 0; mi < 3; ++mi)
#pragma unroll
      for (int ni = 0; ni < 3; ++ni)
        acc[mi][ni] = __builtin_amdgcn_mfma_f32_16x16x32_bf16(a[mi], bb[ni], acc[mi][ni], 0, 0, 0);
  }

  size_t sb = ((size_t)((((b * 8 + h) * 16) + kc) * 4 + w)) * 2304;
#pragma unroll
  for (int mi = 0; mi < 3; ++mi)
#pragma unroll
    for (int ni = 0; ni < 3; ++ni)
#pragma unroll
      for (int r = 0; r < 4; ++r) {
        int c = mi * 16 + lg * 4 + r, d = ni * 16 + lr;
        spart[sb + c * 48 + d] = acc[mi][ni][r];
      }
}

// ---------------------------------------------------------------------------
// k7: reduce partials + scale + softmax -> P~ [b][384][96] bf16.
// ---------------------------------------------------------------------------
__global__ void k7_sm(const float* __restrict__ spart, const float* __restrict__ temp,
                      const float* __restrict__ rnq, const float* __restrict__ rnk,
                      u16* __restrict__ ptil) {
  int h = blockIdx.x, b = blockIdx.y, tid = threadIdx.x;
  int g = h >> 2;
  __shared__ float S[2304];
  size_t base = ((size_t)((b * 8 + h) * 64)) * 2304;
  for (int e = tid; e < 2304; e += 64) {
    float s = 0.f;
    for (int j = 0; j < 64; ++j) s += spart[base + (size_t)j * 2304 + e];
    S[e] = s;
  }
  __syncthreads();
  if (tid < 48) {
    int c = tid;
    float sq = temp[h] * rnq[b * 384 + h * 48 + c];
    float mx = -1e30f;
    for (int d = 0; d < 48; ++d) {
      float v = S[c * 48 + d] * sq * rnk[b * 96 + g * 48 + d];
      mx = fmaxf(mx, v);
    }
    float sum = 0.f;
    for (int d = 0; d < 48; ++d) {
      float v = S[c * 48 + d] * sq * rnk[b * 96 + g * 48 + d];
      sum += __expf(v - mx);
    }
    float inv = 1.f / sum;
    u16* row = ptil + ((size_t)(b * 384 + h * 48 + c)) * 96;
    for (int dk = 0; dk < 96; ++dk) {
      int d = dk - g * 48;
      float pv = 0.f;
      if (d >= 0 && d < 48) {
        float v = S[c * 48 + d] * sq * rnk[b * 96 + g * 48 + d];
        pv = __expf(v - mx) * inv;
      }
      row[dk] = f2b(pv);
    }
  }
}

// ---------------------------------------------------------------------------
// k8: Yt[p][c] = sum_dk vt[p][dk] * P~[c][dk].  grid (128, 8), 512 thr.
// ---------------------------------------------------------------------------
__global__ __launch_bounds__(512) void k8_pv(const u16* __restrict__ vt,
                                             const u16* __restrict__ ptil,
                                             u16* __restrict__ yt) {
  int ptb = blockIdx.x, b = blockIdx.y;
  int tid = threadIdx.x;
  int w = tid >> 6, l = tid & 63, lr = l & 15, lg = l >> 4;
  int wm = w >> 2, wn = w & 3;

  f32x4 acc[4][6] = {};
  size_t arow0 = ((size_t)(b * HW + ptb * 128 + wm * 64 + lr)) * 96;
  size_t brow0 = ((size_t)(b * CDIM + wn * 96 + lr)) * 96;

  for (int ks = 0; ks < 3; ++ks) {
    int ko = ks * 32 + lg * 8;
    s16x8 a[4], bb[6];
#pragma unroll
    for (int mf = 0; mf < 4; ++mf) a[mf] = *(const s16x8*)(vt + arow0 + (size_t)mf * 16 * 96 + ko);
#pragma unroll
    for (int nf = 0; nf < 6; ++nf) bb[nf] = *(const s16x8*)(ptil + brow0 + (size_t)nf * 16 * 96 + ko);
#pragma unroll
    for (int mf = 0; mf < 4; ++mf)
#pragma unroll
      for (int nf = 0; nf < 6; ++nf)
        acc[mf][nf] = __builtin_amdgcn_mfma_f32_16x16x32_bf16(a[mf], bb[nf], acc[mf][nf], 0, 0, 0);
  }

#pragma unroll
  for (int mf = 0; mf < 4; ++mf)
#pragma unroll
    for (int nf = 0; nf < 6; ++nf)
#pragma unroll
      for (int r = 0; r < 4; ++r) {
        int p = ptb * 128 + wm * 64 + mf * 16 + lg * 4 + r;
        int c = wn * 96 + nf * 16 + lr;
        yt[((size_t)(b * HW + p)) * 384 + c] = f2b(acc[mf][nf][r]);
      }
}

// ---------------------------------------------------------------------------
extern "C" void kernel_launch(void* const* d_in, const int* in_sizes, int n_in,
                              void* d_out, int out_size, void* d_ws, size_t ws_size,
                              hipStream_t stream) {
  const float* q    = (const float*)d_in[0];
  const float* k    = (const float*)d_in[1];
  const float* w_q  = (const float*)d_in[2];
  const float* w_kv = (const float*)d_in[3];
  const float* w_qd = (const float*)d_in[4];
  const float* w_kd = (const float*)d_in[5];
  const float* w_o  = (const float*)d_in[6];
  const float* temp = (const float*)d_in[7];
  const float* lnqw = (const float*)d_in[8];
  const float* lnqb = (const float*)d_in[9];
  const float* lnkw = (const float*)d_in[10];
  const float* lnkb = (const float*)d_in[11];
  float* out = (float*)d_out;

  char* ws = (char*)d_ws;
  size_t off = 0;
  auto alloc = [&](size_t bytes) -> void* {
    void* p = ws + off;
    off += (bytes + 255) & ~(size_t)255;
    return p;
  };

  u16*   wqp   = (u16*)alloc(384 * 384 * 2);
  float* rwsQ  = (float*)alloc(384 * 4);
  float* biasQ = (float*)alloc(384 * 4);
  u16*   wkvp  = (u16*)alloc(256 * 384 * 2);   // padded to 256 rows
  float* rwsKV = (float*)alloc(256 * 4);
  float* biasKV= (float*)alloc(256 * 4);
  u16*   wop   = (u16*)alloc(384 * 384 * 2);
  u16*   qp    = (u16*)alloc((size_t)NB * CDIM * HW * 2);  // aliased as yt later
  u16*   kvp   = (u16*)alloc((size_t)NB * KVC * HW * 2);
  u16*   qd    = (u16*)alloc((size_t)NB * CDIM * HW * 2);
  u16*   kvd   = (u16*)alloc((size_t)NB * KVC * HW * 2);
  u16*   vt    = (u16*)alloc((size_t)NB * HW * 96 * 2);
  float* spart = (float*)alloc((size_t)4096 * 2304 * 4);
  u16*   ptil  = (u16*)alloc((size_t)NB * CDIM * 96 * 2);
  float* rnq   = (float*)alloc((size_t)NB * 384 * 4);
  float* rnk   = (float*)alloc((size_t)NB * 96 * 4);

  // lifetime alias (sequential stream => safe): qp dead after k4
  u16* yt = qp;

  k0_prep<<<4, 256, 0, stream>>>(w_q, w_kv, w_o, lnqw, lnqb, lnkw, lnkb,
                                 wqp, rwsQ, biasQ, wkvp, rwsKV, biasKV, wop);

  gemm_fused<0><<<dim3(128, 3, NB), 256, 0, stream>>>(wqp, q, rwsQ, biasQ, qp, 384);
  gemm_fused<0><<<dim3(128, 2, NB), 256, 0, stream>>>(wkvp, k, rwsKV, biasKV, kvp, 192);

  k4_dw<<<dim3(576, NB), 256, 0, stream>>>(qp, kvp, w_qd, w_kd, qd, kvd, rnq, rnk);

  k5b_vt<<<dim3(64, NB), 256, 0, stream>>>(kvd, vt);

  k6_qk<<<dim3(16, 8, NB), 256, 0, stream>>>(qd, kvd, spart);
  k7_sm<<<dim3(8, NB), 64, 0, stream>>>(spart, temp, rnq, rnk, ptil);

  k8_pv<<<dim3(128, NB), 512, 0, stream>>>(vt, ptil, yt);

  gemm_fused<1><<<dim3(128, 3, NB), 256, 0, stream>>>(wop, yt, nullptr, nullptr, out, 384);
}

// Round 6
// 616.467 us; speedup vs baseline: 1.6728x; 1.1059x over previous
//
#include <hip/hip_runtime.h>
#include <math.h>

// ---------------------------------------------------------------------------
// CrossGroupedQueryAttention on MI355X — round 6
//
// R5 post-mortem: dbuf/1-barrier gave only 6%; GEMMs are latency-chain x
// low-TLP bound (occ 22% <- 164 regs incl 64 AGPR; ~3.3K cy per block-iter).
// This round: tile 128x64 (acc[4][2]=32 AGPR, launch_bounds(256,4) -> 4
// blocks/CU), A-panel + MODE1-B staged via global_load_lds (async, no reg
// round-trip), XOR-swizzled LDS (pre-swizzled gll SOURCE + same-XOR reads;
// s(r)=(r&3)^((r>>2)&3)^((r>>4)&3) -> conflict-free frag reads/writes).
// ---------------------------------------------------------------------------

typedef unsigned short u16;
typedef unsigned int u32;
typedef short s16x8 __attribute__((ext_vector_type(8)));
typedef float f32x4 __attribute__((ext_vector_type(4)));

#define HW 16384
#define NB 8
#define CDIM 384
#define KVC 192

__device__ __forceinline__ float b2f(u16 u) {
  return __uint_as_float(((u32)u) << 16);
}
__device__ __forceinline__ u16 f2b(float f) {
  u32 u = __float_as_uint(f);
  u += 0x7fffu + ((u >> 16) & 1u);   // RNE
  return (u16)(u >> 16);
}
__device__ __forceinline__ int swz(int r) {          // LDS chunk swizzle
  return (r & 3) ^ ((r >> 2) & 3) ^ ((r >> 4) & 3);
}
__device__ __forceinline__ void gll16(const void* g, void* l) {
  __builtin_amdgcn_global_load_lds(
      (const __attribute__((address_space(1))) u32*)g,
      (__attribute__((address_space(3))) u32*)l, 16, 0, 0);
}

// ---------------------------------------------------------------------------
// k0: fold LN weights into conv weights.  1024 threads.
// ---------------------------------------------------------------------------
__global__ void k0_prep(const float* __restrict__ wq, const float* __restrict__ wkv,
                        const float* __restrict__ wo,
                        const float* __restrict__ lnqw, const float* __restrict__ lnqb,
                        const float* __restrict__ lnkw, const float* __restrict__ lnkb,
                        u16* __restrict__ wqp, float* __restrict__ rwsQ, float* __restrict__ biasQ,
                        u16* __restrict__ wkvp, float* __restrict__ rwsKV, float* __restrict__ biasKV,
                        u16* __restrict__ wop) {
  int r = blockIdx.x * 256 + threadIdx.x;
  if (r < 384) {
    float rs = 0.f, bs = 0.f;
    for (int i = 0; i < 384; ++i) {
      float wp = wq[r * 384 + i] * lnqw[i];
      u16 h = f2b(wp);
      rs += b2f(h);
      bs += wq[r * 384 + i] * lnqb[i];
      wqp[r * 384 + i] = h;
    }
    rwsQ[r] = rs; biasQ[r] = bs;
  } else if (r < 640) {
    int o = r - 384;
    if (o < 192) {
      float rs = 0.f, bs = 0.f;
      for (int i = 0; i < 384; ++i) {
        float wp = wkv[o * 384 + i] * lnkw[i];
        u16 h = f2b(wp);
        rs += b2f(h);
        bs += wkv[o * 384 + i] * lnkb[i];
        wkvp[o * 384 + i] = h;
      }
      rwsKV[o] = rs; biasKV[o] = bs;
    } else {
      for (int i = 0; i < 384; ++i) wkvp[o * 384 + i] = 0;
      rwsKV[o] = 0.f; biasKV[o] = 0.f;
    }
  } else {
    int o = r - 640;
    for (int i = 0; i < 384; ++i) wop[o * 384 + i] = f2b(wo[o * 384 + i]);
  }
}

// ---------------------------------------------------------------------------
// gemm_fused: D[o][p] = sum_k A[o][k]*B[p][k], K=384, tile 128o x 64p,
// 4 waves (2x2), wave-tile 64x32, acc[4][2]=32 AGPR.
// A: global_load_lds 8KB/step (pre-swizzled source), dbuf.
// MODE 0: B from f32 NCHW, reg-staged+cvt+stats, ds_write swizzled; LN epi.
// MODE 1: B (yt bf16 [p][384]) via global_load_lds too; plain f32 out.
// LDS layout [row][32] u16 linear; global chunk c stored at (c ^ swz(row)).
// ---------------------------------------------------------------------------
template <int MODE>
__global__ __launch_bounds__(256, 4) void gemm_fused(const u16* __restrict__ A,
                                                     const void* __restrict__ Bsrc,
                                                     const float* __restrict__ rowsum,
                                                     const float* __restrict__ bias,
                                                     void* __restrict__ outv, int M) {
  __shared__ u16 tA[2][128 * 32];
  __shared__ u16 tB[2][64 * 32];
  __shared__ float2 sred[4][64];
  __shared__ float muL[64], sdL[64];

  const int b = blockIdx.z, ot = blockIdx.y, pt = blockIdx.x;
  const int tid = threadIdx.x;
  const int w = tid >> 6, l = tid & 63;
  const int wm = w >> 1, wn = w & 1, lr = l & 15, lg = l >> 4;

  f32x4 acc[4][2] = {};

  // ---- A gll mapping: 2 issues, chunk index ci = i*256 + tid
  const int rA0 = tid >> 2, cA0 = tid & 3;
  const int rA1 = (256 + tid) >> 2, cA1 = tid & 3;   // (256+tid)&3 == tid&3
  const u16* aS0 = A + (size_t)(ot * 128 + rA0) * 384 + (cA0 ^ swz(rA0)) * 8;
  const u16* aS1 = A + (size_t)(ot * 128 + rA1) * 384 + (cA1 ^ swz(rA1)) * 8;
  const int aDst0 = (w * 64) * 8;            // u16 index within tA[buf]
  const int aDst1 = (256 + w * 64) * 8;

  // ---- B staging mappings
  const float* Bf = (const float*)Bsrc;
  const u16* Bh = (const u16*)Bsrc;
  // MODE 0: thread t -> pixel l, channel group w (8 ch), f32 NCHW coalesced
  const size_t fbase = (size_t)b * CDIM * HW + (size_t)pt * 64 + l;
  const int bWrChunk = w ^ swz(l);           // LDS chunk for this thread's 8 ch
  // MODE 1: gll, chunk index = tid: row tid>>2, chunk tid&3
  const int rB = tid >> 2, cB = tid & 3;
  const u16* bS = Bh + ((size_t)(b * HW + pt * 64 + rB)) * 384 + (cB ^ swz(rB)) * 8;
  const int bDst = (w * 64) * 8;

  float pv[8];
  float sum = 0.f, sq = 0.f;

  auto stageA = [&](int ks, int buf) {
    gll16(aS0 + ks * 32, &tA[buf][aDst0]);
    gll16(aS1 + ks * 32, &tA[buf][aDst1]);
  };
  auto loadB = [&](int ks) {
    if (MODE == 0) {
#pragma unroll
      for (int e = 0; e < 8; ++e)
        pv[e] = Bf[fbase + (size_t)(ks * 32 + w * 8 + e) * HW];
    } else {
      gll16(bS + ks * 32, &tB[0][0] + (size_t)0);   // placeholder, not used
    }
  };
  auto stageB1 = [&](int ks, int buf) {   // MODE 1 async stage
    gll16(bS + ks * 32, &tB[buf][bDst]);
  };
  auto storeB0 = [&](int buf) {           // MODE 0 cvt + stats + ds_write
    u32 pk[4];
#pragma unroll
    for (int e = 0; e < 8; e += 2) {
      float v0 = pv[e], v1 = pv[e + 1];
      sum += v0 + v1;
      sq += v0 * v0 + v1 * v1;
      pk[e >> 1] = (u32)f2b(v0) | ((u32)f2b(v1) << 16);
    }
    *(uint4*)&tB[buf][l * 32 + bWrChunk * 8] = make_uint4(pk[0], pk[1], pk[2], pk[3]);
  };

  // ---- prologue: stage k-step 0 into buf 0
  stageA(0, 0);
  if (MODE == 0) { loadB(0); storeB0(0); }
  else { stageB1(0, 0); }
  __syncthreads();

  int cur = 0;
  for (int ks = 0; ks < 12; ++ks) {
    // issue next-step staging first (latency spans this step's compute)
    if (ks < 11) {
      stageA(ks + 1, cur ^ 1);
      if (MODE == 0) loadB(ks + 1);
      else stageB1(ks + 1, cur ^ 1);
    }

    // fragments from tile[cur] (swizzled reads)
    s16x8 a[4], bb[2];
#pragma unroll
    for (int mf = 0; mf < 4; ++mf) {
      int row = wm * 64 + mf * 16 + lr;
      a[mf] = *(const s16x8*)&tA[cur][row * 32 + (lg ^ swz(row)) * 8];
    }
#pragma unroll
    for (int nf = 0; nf < 2; ++nf) {
      int row = wn * 32 + nf * 16 + lr;
      bb[nf] = *(const s16x8*)&tB[cur][row * 32 + (lg ^ swz(row)) * 8];
    }
#pragma unroll
    for (int mf = 0; mf < 4; ++mf)
#pragma unroll
      for (int nf = 0; nf < 2; ++nf)
        acc[mf][nf] = __builtin_amdgcn_mfma_f32_16x16x32_bf16(a[mf], bb[nf], acc[mf][nf], 0, 0, 0);

    if (ks < 11 && MODE == 0) storeB0(cur ^ 1);
    __syncthreads();   // drains vmcnt (gll) + publishes cur^1, protects cur
    cur ^= 1;
  }

  // ---- LN stats combine (MODE 0): 4 channel-groups per pixel
  if (MODE == 0) {
    sred[w][l] = make_float2(sum, sq);
    __syncthreads();
    if (tid < 64) {
      float s = 0.f, q2 = 0.f;
#pragma unroll
      for (int g = 0; g < 4; ++g) { s += sred[g][tid].x; q2 += sred[g][tid].y; }
      float mn = s * (1.f / 384.f);
      float var = q2 * (1.f / 384.f) - mn * mn;
      muL[tid] = mn;
      sdL[tid] = rsqrtf(var + 1e-5f);
    }
    __syncthreads();
  }

  // ---- epilogue
#pragma unroll
  for (int nf = 0; nf < 2; ++nf) {
    int row = wn * 32 + nf * 16 + lr;
    int p = pt * 64 + row;
    float m_ = 0.f, s_ = 0.f;
    if (MODE == 0) { m_ = muL[row]; s_ = sdL[row]; }
#pragma unroll
    for (int mf = 0; mf < 4; ++mf) {
#pragma unroll
      for (int r = 0; r < 4; ++r) {
        int o = ot * 128 + wm * 64 + mf * 16 + lg * 4 + r;
        if (MODE == 0) {
          if (o < M) {
            float v = s_ * (acc[mf][nf][r] - m_ * rowsum[o]) + bias[o];
            ((u16*)outv)[((size_t)(b * M + o)) * HW + p] = f2b(v);
          }
        } else {
          ((float*)outv)[((size_t)(b * CDIM + o)) * HW + p] = acc[mf][nf][r];
        }
      }
    }
  }
}

// ---------------------------------------------------------------------------
// k4: depthwise 3x3 (zero pad), LDS-staged plane + fused row l2-norm.
// ---------------------------------------------------------------------------
__global__ __launch_bounds__(256) void k4_dw(const u16* __restrict__ qp, const u16* __restrict__ kvp,
                                             const float* __restrict__ wqdw, const float* __restrict__ wkvdw,
                                             u16* __restrict__ qd, u16* __restrict__ kvd,
                                             float* __restrict__ rnq, float* __restrict__ rnk) {
  __shared__ u16 plane[16384];     // 32 KB
  __shared__ float red[256];

  int c = blockIdx.x, b = blockIdx.y;
  int tid = threadIdx.x;
  const u16* in; u16* outb; const float* wp; int C;
  int isQ = (c < 384), cc = isQ ? c : c - 384;
  if (isQ) { in = qp; outb = qd; wp = wqdw + cc * 9; C = CDIM; }
  else     { in = kvp; outb = kvd; wp = wkvdw + cc * 9; C = KVC; }
  size_t base = ((size_t)(b * C + cc)) * HW;

  float w[9];
#pragma unroll
  for (int j = 0; j < 9; ++j) w[j] = wp[j];

  const uint4* gsrc = (const uint4*)(in + base);
  uint4* lplane = (uint4*)plane;
#pragma unroll
  for (int i = 0; i < 8; ++i) lplane[tid + i * 256] = gsrc[tid + i * 256];
  __syncthreads();

  uint4* gdst = (uint4*)(outb + base);
  float ns = 0.f;
#pragma unroll
  for (int it = 0; it < 8; ++it) {
    int idx = tid + it * 256;
    int y = idx >> 4, ox = idx & 15;
    int x0 = ox * 8;

    float r[3][10];
#pragma unroll
    for (int rr = 0; rr < 3; ++rr) {
      int yy = y + rr - 1;
      if ((unsigned)yy < 128u) {
        int rbase = yy * 128 + x0;
        r[rr][0] = (x0 > 0) ? b2f(plane[rbase - 1]) : 0.f;
        uint4 v = *(const uint4*)&plane[rbase];
        u32 ws[4] = {v.x, v.y, v.z, v.w};
#pragma unroll
        for (int j = 0; j < 4; ++j) {
          r[rr][1 + 2 * j] = b2f((u16)(ws[j] & 0xffff));
          r[rr][2 + 2 * j] = b2f((u16)(ws[j] >> 16));
        }
        r[rr][9] = (x0 < 120) ? b2f(plane[rbase + 8]) : 0.f;
      } else {
#pragma unroll
        for (int j = 0; j < 10; ++j) r[rr][j] = 0.f;
      }
    }

    u32 packed[4];
#pragma unroll
    for (int j = 0; j < 8; ++j) {
      float a = 0.f;
#pragma unroll
      for (int rr = 0; rr < 3; ++rr)
#pragma unroll
        for (int dx = 0; dx < 3; ++dx)
          a += w[rr * 3 + dx] * r[rr][j + dx];
      u16 h = f2b(a);
      float hv = b2f(h);
      ns += hv * hv;
      if (j & 1) packed[j >> 1] |= ((u32)h) << 16; else packed[j >> 1] = (u32)h;
    }
    gdst[idx] = make_uint4(packed[0], packed[1], packed[2], packed[3]);
  }

  red[tid] = ns;
  __syncthreads();
  for (int st = 128; st > 0; st >>= 1) {
    if (tid < st) red[tid] += red[tid + st];
    __syncthreads();
  }
  if (tid == 0) {
    float n = sqrtf(red[0]);
    float inv = 1.f / fmaxf(n, 1e-12f);
    if (isQ) rnq[b * 384 + cc] = inv;
    else if (cc < 96) rnk[b * 96 + cc] = inv;
  }
}

// ---------------------------------------------------------------------------
// k5b: transpose v (kvd rows 96..191) -> vt [b][p][96] bf16. grid (64, 8).
// ---------------------------------------------------------------------------
__global__ void k5b_vt(const u16* __restrict__ kvd, u16* __restrict__ vt) {
  int p = blockIdx.x * 256 + threadIdx.x;
  int b = blockIdx.y;
  size_t sb = ((size_t)(b * KVC + 96)) * HW + p;
  uint4* dv = (uint4*)vt + ((size_t)(b * HW + p)) * 12;
  for (int j8 = 0; j8 < 12; ++j8) {
    u32 w[4];
#pragma unroll
    for (int j = 0; j < 8; ++j) {
      u16 h = kvd[sb + (size_t)(j8 * 8 + j) * HW];
      if (j & 1) w[j >> 1] |= ((u32)h) << 16; else w[j >> 1] = (u32)h;
    }
    dv[j8] = make_uint4(w[0], w[1], w[2], w[3]);
  }
}

// ---------------------------------------------------------------------------
// k6: split-K QK^T partials. grid (16, 8, 8).
// ---------------------------------------------------------------------------
__global__ __launch_bounds__(256) void k6_qk(const u16* __restrict__ qd,
                                             const u16* __restrict__ kvd,
                                             float* __restrict__ spart) {
  int kc = blockIdx.x, h = blockIdx.y, b = blockIdx.z;
  int tid = threadIdx.x;
  int w = tid >> 6, l = tid & 63, lr = l & 15, lg = l >> 4;
  int g = h >> 2;
  int p0 = kc * 1024 + w * 256;

  f32x4 acc[3][3] = {};
  size_t qbase = ((size_t)(b * CDIM + h * 48 + lr)) * HW;
  size_t kbase = ((size_t)(b * KVC + g * 48 + lr)) * HW;

  for (int ks = 0; ks < 8; ++ks) {
    int pp = p0 + ks * 32 + lg * 8;
    s16x8 a[3], bb[3];
#pragma unroll
    for (int mi = 0; mi < 3; ++mi) a[mi] = *(const s16x8*)(qd + qbase + (size_t)mi * 16 * HW + pp);
#pragma unroll
    for (int ni = 0; ni < 3; ++ni) bb[ni] = *(const s16x8*)(kvd + kbase + (size_t)ni * 16 * HW + pp);
#pragma unroll
    for (int mi = 0; mi < 3; ++mi)
#pragma unroll
      for (int ni = 0; ni < 3; ++ni)
        acc[mi][ni] = __builtin_amdgcn_mfma_f32_16x16x32_bf16(a[mi], bb[ni], acc[mi][ni], 0, 0, 0);
  }

  size_t sb = ((size_t)((((b * 8 + h) * 16) + kc) * 4 + w)) * 2304;
#pragma unroll
  for (int mi = 0; mi < 3; ++mi)
#pragma unroll
    for (int ni = 0; ni < 3; ++ni)
#pragma unroll
      for (int r = 0; r < 4; ++r) {
        int c = mi * 16 + lg * 4 + r, d = ni * 16 + lr;
        spart[sb + c * 48 + d] = acc[mi][ni][r];
      }
}

// ---------------------------------------------------------------------------
// k7: reduce partials + scale + softmax -> P~ [b][384][96] bf16.
// ---------------------------------------------------------------------------
__global__ void k7_sm(const float* __restrict__ spart, const float* __restrict__ temp,
                      const float* __restrict__ rnq, const float* __restrict__ rnk,
                      u16* __restrict__ ptil) {
  int h = blockIdx.x, b = blockIdx.y, tid = threadIdx.x;
  int g = h >> 2;
  __shared__ float S[2304];
  size_t base = ((size_t)((b * 8 + h) * 64)) * 2304;
  for (int e = tid; e < 2304; e += 64) {
    float s = 0.f;
    for (int j = 0; j < 64; ++j) s += spart[base + (size_t)j * 2304 + e];
    S[e] = s;
  }
  __syncthreads();
  if (tid < 48) {
    int c = tid;
    float sq = temp[h] * rnq[b * 384 + h * 48 + c];
    float mx = -1e30f;
    for (int d = 0; d < 48; ++d) {
      float v = S[c * 48 + d] * sq * rnk[b * 96 + g * 48 + d];
      mx = fmaxf(mx, v);
    }
    float sum = 0.f;
    for (int d = 0; d < 48; ++d) {
      float v = S[c * 48 + d] * sq * rnk[b * 96 + g * 48 + d];
      sum += __expf(v - mx);
    }
    float inv = 1.f / sum;
    u16* row = ptil + ((size_t)(b * 384 + h * 48 + c)) * 96;
    for (int dk = 0; dk < 96; ++dk) {
      int d = dk - g * 48;
      float pv = 0.f;
      if (d >= 0 && d < 48) {
        float v = S[c * 48 + d] * sq * rnk[b * 96 + g * 48 + d];
        pv = __expf(v - mx) * inv;
      }
      row[dk] = f2b(pv);
    }
  }
}

// ---------------------------------------------------------------------------
// k8: Yt[p][c] = sum_dk vt[p][dk] * P~[c][dk].  grid (128, 8), 512 thr.
// ---------------------------------------------------------------------------
__global__ __launch_bounds__(512) void k8_pv(const u16* __restrict__ vt,
                                             const u16* __restrict__ ptil,
                                             u16* __restrict__ yt) {
  int ptb = blockIdx.x, b = blockIdx.y;
  int tid = threadIdx.x;
  int w = tid >> 6, l = tid & 63, lr = l & 15, lg = l >> 4;
  int wm = w >> 2, wn = w & 3;

  f32x4 acc[4][6] = {};
  size_t arow0 = ((size_t)(b * HW + ptb * 128 + wm * 64 + lr)) * 96;
  size_t brow0 = ((size_t)(b * CDIM + wn * 96 + lr)) * 96;

  for (int ks = 0; ks < 3; ++ks) {
    int ko = ks * 32 + lg * 8;
    s16x8 a[4], bb[6];
#pragma unroll
    for (int mf = 0; mf < 4; ++mf) a[mf] = *(const s16x8*)(vt + arow0 + (size_t)mf * 16 * 96 + ko);
#pragma unroll
    for (int nf = 0; nf < 6; ++nf) bb[nf] = *(const s16x8*)(ptil + brow0 + (size_t)nf * 16 * 96 + ko);
#pragma unroll
    for (int mf = 0; mf < 4; ++mf)
#pragma unroll
      for (int nf = 0; nf < 6; ++nf)
        acc[mf][nf] = __builtin_amdgcn_mfma_f32_16x16x32_bf16(a[mf], bb[nf], acc[mf][nf], 0, 0, 0);
  }

#pragma unroll
  for (int mf = 0; mf < 4; ++mf)
#pragma unroll
    for (int nf = 0; nf < 6; ++nf)
#pragma unroll
      for (int r = 0; r < 4; ++r) {
        int p = ptb * 128 + wm * 64 + mf * 16 + lg * 4 + r;
        int c = wn * 96 + nf * 16 + lr;
        yt[((size_t)(b * HW + p)) * 384 + c] = f2b(acc[mf][nf][r]);
      }
}

// ---------------------------------------------------------------------------
extern "C" void kernel_launch(void* const* d_in, const int* in_sizes, int n_in,
                              void* d_out, int out_size, void* d_ws, size_t ws_size,
                              hipStream_t stream) {
  const float* q    = (const float*)d_in[0];
  const float* k    = (const float*)d_in[1];
  const float* w_q  = (const float*)d_in[2];
  const float* w_kv = (const float*)d_in[3];
  const float* w_qd = (const float*)d_in[4];
  const float* w_kd = (const float*)d_in[5];
  const float* w_o  = (const float*)d_in[6];
  const float* temp = (const float*)d_in[7];
  const float* lnqw = (const float*)d_in[8];
  const float* lnqb = (const float*)d_in[9];
  const float* lnkw = (const float*)d_in[10];
  const float* lnkb = (const float*)d_in[11];
  float* out = (float*)d_out;

  char* ws = (char*)d_ws;
  size_t off = 0;
  auto alloc = [&](size_t bytes) -> void* {
    void* p = ws + off;
    off += (bytes + 255) & ~(size_t)255;
    return p;
  };

  u16*   wqp   = (u16*)alloc(384 * 384 * 2);
  float* rwsQ  = (float*)alloc(384 * 4);
  float* biasQ = (float*)alloc(384 * 4);
  u16*   wkvp  = (u16*)alloc(256 * 384 * 2);   // padded to 256 rows
  float* rwsKV = (float*)alloc(256 * 4);
  float* biasKV= (float*)alloc(256 * 4);
  u16*   wop   = (u16*)alloc(384 * 384 * 2);
  u16*   qp    = (u16*)alloc((size_t)NB * CDIM * HW * 2);  // aliased as yt later
  u16*   kvp   = (u16*)alloc((size_t)NB * KVC * HW * 2);
  u16*   qd    = (u16*)alloc((size_t)NB * CDIM * HW * 2);
  u16*   kvd   = (u16*)alloc((size_t)NB * KVC * HW * 2);
  u16*   vt    = (u16*)alloc((size_t)NB * HW * 96 * 2);
  float* spart = (float*)alloc((size_t)4096 * 2304 * 4);
  u16*   ptil  = (u16*)alloc((size_t)NB * CDIM * 96 * 2);
  float* rnq   = (float*)alloc((size_t)NB * 384 * 4);
  float* rnk   = (float*)alloc((size_t)NB * 96 * 4);

  // lifetime alias (sequential stream => safe): qp dead after k4
  u16* yt = qp;

  k0_prep<<<4, 256, 0, stream>>>(w_q, w_kv, w_o, lnqw, lnqb, lnkw, lnkb,
                                 wqp, rwsQ, biasQ, wkvp, rwsKV, biasKV, wop);

  gemm_fused<0><<<dim3(256, 3, NB), 256, 0, stream>>>(wqp, q, rwsQ, biasQ, qp, 384);
  gemm_fused<0><<<dim3(256, 2, NB), 256, 0, stream>>>(wkvp, k, rwsKV, biasKV, kvp, 192);

  k4_dw<<<dim3(576, NB), 256, 0, stream>>>(qp, kvp, w_qd, w_kd, qd, kvd, rnq, rnk);

  k5b_vt<<<dim3(64, NB), 256, 0, stream>>>(kvd, vt);

  k6_qk<<<dim3(16, 8, NB), 256, 0, stream>>>(qd, kvd, spart);
  k7_sm<<<dim3(8, NB), 64, 0, stream>>>(spart, temp, rnq, rnk, ptil);

  k8_pv<<<dim3(128, NB), 512, 0, stream>>>(vt, ptil, yt);

  gemm_fused<1><<<dim3(256, 3, NB), 256, 0, stream>>>(wop, yt, nullptr, nullptr, out, 384);
}

// Round 7
// 613.841 us; speedup vs baseline: 1.6800x; 1.0043x over previous
//
#include <hip/hip_runtime.h>
#include <math.h>

// ---------------------------------------------------------------------------
// CrossGroupedQueryAttention on MI355X — round 7
//
// R6 post-mortem: GEMMs still latency-bound (kv-proj same 165us as q-proj
// with 2/3 the blocks; 1375cy wall per block-step vs ~40cy MFMA; occ 52%).
// Root cause: __syncthreads drains vmcnt(0) every K-step -> each barrier
// eats ~1 HBM latency. Fix (this round's single structural change):
// depth-2 prefetch, 3 LDS buffers, fully-unrolled K loop, counted
// s_waitcnt vmcnt(N) + raw s_barrier (N = in-flight loads for step ks+2:
// MODE0 10, MODE1 3). Loads now span ~2 iterations before being waited on.
// Bank conflicts (7M, ~7% of wall) noted, not chased.
// ---------------------------------------------------------------------------

typedef unsigned short u16;
typedef unsigned int u32;
typedef short s16x8 __attribute__((ext_vector_type(8)));
typedef float f32x4 __attribute__((ext_vector_type(4)));

#define HW 16384
#define NB 8
#define CDIM 384
#define KVC 192

__device__ __forceinline__ float b2f(u16 u) {
  return __uint_as_float(((u32)u) << 16);
}
__device__ __forceinline__ u16 f2b(float f) {
  u32 u = __float_as_uint(f);
  u += 0x7fffu + ((u >> 16) & 1u);   // RNE
  return (u16)(u >> 16);
}
__device__ __forceinline__ int swz(int r) {          // LDS chunk swizzle
  return (r & 3) ^ ((r >> 2) & 3) ^ ((r >> 4) & 3);
}
__device__ __forceinline__ void gll16(const void* g, void* l) {
  __builtin_amdgcn_global_load_lds(
      (const __attribute__((address_space(1))) u32*)g,
      (__attribute__((address_space(3))) u32*)l, 16, 0, 0);
}

// ---------------------------------------------------------------------------
// k0: fold LN weights into conv weights.  1024 threads.
// ---------------------------------------------------------------------------
__global__ void k0_prep(const float* __restrict__ wq, const float* __restrict__ wkv,
                        const float* __restrict__ wo,
                        const float* __restrict__ lnqw, const float* __restrict__ lnqb,
                        const float* __restrict__ lnkw, const float* __restrict__ lnkb,
                        u16* __restrict__ wqp, float* __restrict__ rwsQ, float* __restrict__ biasQ,
                        u16* __restrict__ wkvp, float* __restrict__ rwsKV, float* __restrict__ biasKV,
                        u16* __restrict__ wop) {
  int r = blockIdx.x * 256 + threadIdx.x;
  if (r < 384) {
    float rs = 0.f, bs = 0.f;
    for (int i = 0; i < 384; ++i) {
      float wp = wq[r * 384 + i] * lnqw[i];
      u16 h = f2b(wp);
      rs += b2f(h);
      bs += wq[r * 384 + i] * lnqb[i];
      wqp[r * 384 + i] = h;
    }
    rwsQ[r] = rs; biasQ[r] = bs;
  } else if (r < 640) {
    int o = r - 384;
    if (o < 192) {
      float rs = 0.f, bs = 0.f;
      for (int i = 0; i < 384; ++i) {
        float wp = wkv[o * 384 + i] * lnkw[i];
        u16 h = f2b(wp);
        rs += b2f(h);
        bs += wkv[o * 384 + i] * lnkb[i];
        wkvp[o * 384 + i] = h;
      }
      rwsKV[o] = rs; biasKV[o] = bs;
    } else {
      for (int i = 0; i < 384; ++i) wkvp[o * 384 + i] = 0;
      rwsKV[o] = 0.f; biasKV[o] = 0.f;
    }
  } else {
    int o = r - 640;
    for (int i = 0; i < 384; ++i) wop[o * 384 + i] = f2b(wo[o * 384 + i]);
  }
}

// ---------------------------------------------------------------------------
// gemm_fused: D[o][p] = sum_k A[o][k]*B[p][k], K=384, tile 128o x 64p,
// 4 waves (2x2), wave-tile 64x32, acc[4][2].
// 3 LDS buffers, depth-2 prefetch, counted-vmcnt + raw s_barrier per step.
// A: global_load_lds (pre-swizzled source). MODE 0: B f32 NCHW reg-staged
// (pv[2][8] 2-deep) + LN stats + swizzled ds_write; LN epilogue; bf16 out.
// MODE 1: B (yt bf16 [p][384]) via global_load_lds; f32 NCHW out.
// Race audit: gll(ks+2) targets buf (ks+2)%3 == (ks-1)%3, whose readers
// (iter ks-1) finished ds_reads before their MFMA (data dep) hence before
// the iter ks-1 barrier; in-flight gll crossing a barrier lands in a buffer
// not read until the vmcnt wait two barriers later retires it.
// ---------------------------------------------------------------------------
template <int MODE>
__global__ __launch_bounds__(256, 4) void gemm_fused(const u16* __restrict__ A,
                                                     const void* __restrict__ Bsrc,
                                                     const float* __restrict__ rowsum,
                                                     const float* __restrict__ bias,
                                                     void* __restrict__ outv, int M) {
  __shared__ u16 tA[3][128 * 32];
  __shared__ u16 tB[3][64 * 32];
  __shared__ float2 sred[4][64];
  __shared__ float muL[64], sdL[64];

  const int b = blockIdx.z, ot = blockIdx.y, pt = blockIdx.x;
  const int tid = threadIdx.x;
  const int w = tid >> 6, l = tid & 63;
  const int wm = w >> 1, wn = w & 1, lr = l & 15, lg = l >> 4;

  f32x4 acc[4][2] = {};

  // ---- A gll mapping: 2 issues, chunk index ci = i*256 + tid
  const int rA0 = tid >> 2, cA0 = tid & 3;
  const int rA1 = 64 + rA0;
  const u16* aS0 = A + (size_t)(ot * 128 + rA0) * 384 + (cA0 ^ swz(rA0)) * 8;
  const u16* aS1 = A + (size_t)(ot * 128 + rA1) * 384 + (cA0 ^ swz(rA1)) * 8;
  const int aDst0 = (w * 64) * 8;            // u16 index within tA[buf]
  const int aDst1 = (256 + w * 64) * 8;

  // ---- B staging mappings
  const float* Bf = (const float*)Bsrc;
  const u16* Bh = (const u16*)Bsrc;
  // MODE 0: thread t -> pixel l, channel group w (8 ch), f32 NCHW coalesced
  const size_t fbase = (size_t)b * CDIM * HW + (size_t)pt * 64 + l;
  const int bWrChunk = w ^ swz(l);           // LDS chunk for this thread's 8 ch
  // MODE 1: gll, chunk index = tid: row tid>>2, chunk tid&3
  const int rB = tid >> 2;
  const u16* bS = Bh + ((size_t)(b * HW + pt * 64 + rB)) * 384 + ((tid & 3) ^ swz(rB)) * 8;
  const int bDst = (w * 64) * 8;

  float pvbuf[2][8];
  float sum = 0.f, sq = 0.f;

  auto stageA = [&](int ks, int buf) {
    gll16(aS0 + ks * 32, &tA[buf][aDst0]);
    gll16(aS1 + ks * 32, &tA[buf][aDst1]);
  };
  auto stageB1 = [&](int ks, int buf) {   // MODE 1 async stage
    gll16(bS + ks * 32, &tB[buf][bDst]);
  };
  auto loadB0 = [&](int ks, float* pvv) { // MODE 0 reg-stage (8 coalesced f32)
#pragma unroll
    for (int e = 0; e < 8; ++e)
      pvv[e] = Bf[fbase + (size_t)(ks * 32 + w * 8 + e) * HW];
  };
  auto storeB0 = [&](const float* pvv, int buf) { // cvt + stats + swizzled write
    u32 pk[4];
#pragma unroll
    for (int e = 0; e < 8; e += 2) {
      float v0 = pvv[e], v1 = pvv[e + 1];
      sum += v0 + v1;
      sq += v0 * v0 + v1 * v1;
      pk[e >> 1] = (u32)f2b(v0) | ((u32)f2b(v1) << 16);
    }
    *(uint4*)&tB[buf][l * 32 + bWrChunk * 8] = make_uint4(pk[0], pk[1], pk[2], pk[3]);
  };

  // ---- prologue: stage steps 0 and 1
  if (MODE == 0) {
    stageA(0, 0); loadB0(0, pvbuf[0]);
    stageA(1, 1); loadB0(1, pvbuf[1]);
    asm volatile("s_waitcnt vmcnt(10)" ::: "memory");  // step-0 loads retired
    storeB0(pvbuf[0], 0);
    asm volatile("s_waitcnt lgkmcnt(0)" ::: "memory");
  } else {
    stageA(0, 0); stageB1(0, 0);
    stageA(1, 1); stageB1(1, 1);
    asm volatile("s_waitcnt vmcnt(3)" ::: "memory");   // step-0 glls retired
  }
  __builtin_amdgcn_s_barrier();

#pragma unroll
  for (int ks = 0; ks < 12; ++ks) {
    const int cb = ks % 3;
    const int nb_ = (ks + 2) % 3;

    // ---- issue staging for ks+2 (latency spans ~2 iterations)
    if (ks < 10) {
      stageA(ks + 2, nb_);
      if (MODE == 0) loadB0(ks + 2, pvbuf[ks & 1]);
      else stageB1(ks + 2, nb_);
    }

    // ---- fragments from tile[cb] (swizzled reads; offsets const post-unroll)
    s16x8 a[4], bb[2];
#pragma unroll
    for (int mf = 0; mf < 4; ++mf) {
      int row = wm * 64 + mf * 16 + lr;
      a[mf] = *(const s16x8*)&tA[cb][row * 32 + ((lg ^ swz(row)) * 8)];
    }
#pragma unroll
    for (int nf = 0; nf < 2; ++nf) {
      int row = wn * 32 + nf * 16 + lr;
      bb[nf] = *(const s16x8*)&tB[cb][row * 32 + ((lg ^ swz(row)) * 8)];
    }
#pragma unroll
    for (int mf = 0; mf < 4; ++mf)
#pragma unroll
      for (int nf = 0; nf < 2; ++nf)
        acc[mf][nf] = __builtin_amdgcn_mfma_f32_16x16x32_bf16(a[mf], bb[nf], acc[mf][nf], 0, 0, 0);

    // ---- MODE 0: publish step ks+1 (consumes pv loaded last iter)
    if (MODE == 0 && ks < 11) storeB0(pvbuf[(ks + 1) & 1], (ks + 1) % 3);

    // ---- counted waits: keep ks+2's loads in flight across the barrier
    if (MODE == 0) {
      if (ks < 10)      asm volatile("s_waitcnt vmcnt(10) lgkmcnt(0)" ::: "memory");
      else              asm volatile("s_waitcnt vmcnt(0) lgkmcnt(0)" ::: "memory");
    } else {
      if (ks < 10)      asm volatile("s_waitcnt vmcnt(3) lgkmcnt(0)" ::: "memory");
      else              asm volatile("s_waitcnt vmcnt(0) lgkmcnt(0)" ::: "memory");
    }
    __builtin_amdgcn_s_barrier();
  }

  // ---- LN stats combine (MODE 0): 4 channel-groups per pixel
  if (MODE == 0) {
    sred[w][l] = make_float2(sum, sq);
    __syncthreads();
    if (tid < 64) {
      float s = 0.f, q2 = 0.f;
#pragma unroll
      for (int g = 0; g < 4; ++g) { s += sred[g][tid].x; q2 += sred[g][tid].y; }
      float mn = s * (1.f / 384.f);
      float var = q2 * (1.f / 384.f) - mn * mn;
      muL[tid] = mn;
      sdL[tid] = rsqrtf(var + 1e-5f);
    }
    __syncthreads();
  }

  // ---- epilogue
#pragma unroll
  for (int nf = 0; nf < 2; ++nf) {
    int row = wn * 32 + nf * 16 + lr;
    int p = pt * 64 + row;
    float m_ = 0.f, s_ = 0.f;
    if (MODE == 0) { m_ = muL[row]; s_ = sdL[row]; }
#pragma unroll
    for (int mf = 0; mf < 4; ++mf) {
#pragma unroll
      for (int r = 0; r < 4; ++r) {
        int o = ot * 128 + wm * 64 + mf * 16 + lg * 4 + r;
        if (MODE == 0) {
          if (o < M) {
            float v = s_ * (acc[mf][nf][r] - m_ * rowsum[o]) + bias[o];
            ((u16*)outv)[((size_t)(b * M + o)) * HW + p] = f2b(v);
          }
        } else {
          ((float*)outv)[((size_t)(b * CDIM + o)) * HW + p] = acc[mf][nf][r];
        }
      }
    }
  }
}

// ---------------------------------------------------------------------------
// k4: depthwise 3x3 (zero pad), LDS-staged plane + fused row l2-norm.
// ---------------------------------------------------------------------------
__global__ __launch_bounds__(256) void k4_dw(const u16* __restrict__ qp, const u16* __restrict__ kvp,
                                             const float* __restrict__ wqdw, const float* __restrict__ wkvdw,
                                             u16* __restrict__ qd, u16* __restrict__ kvd,
                                             float* __restrict__ rnq, float* __restrict__ rnk) {
  __shared__ u16 plane[16384];     // 32 KB
  __shared__ float red[256];

  int c = blockIdx.x, b = blockIdx.y;
  int tid = threadIdx.x;
  const u16* in; u16* outb; const float* wp; int C;
  int isQ = (c < 384), cc = isQ ? c : c - 384;
  if (isQ) { in = qp; outb = qd; wp = wqdw + cc * 9; C = CDIM; }
  else     { in = kvp; outb = kvd; wp = wkvdw + cc * 9; C = KVC; }
  size_t base = ((size_t)(b * C + cc)) * HW;

  float w[9];
#pragma unroll
  for (int j = 0; j < 9; ++j) w[j] = wp[j];

  const uint4* gsrc = (const uint4*)(in + base);
  uint4* lplane = (uint4*)plane;
#pragma unroll
  for (int i = 0; i < 8; ++i) lplane[tid + i * 256] = gsrc[tid + i * 256];
  __syncthreads();

  uint4* gdst = (uint4*)(outb + base);
  float ns = 0.f;
#pragma unroll
  for (int it = 0; it < 8; ++it) {
    int idx = tid + it * 256;
    int y = idx >> 4, ox = idx & 15;
    int x0 = ox * 8;

    float r[3][10];
#pragma unroll
    for (int rr = 0; rr < 3; ++rr) {
      int yy = y + rr - 1;
      if ((unsigned)yy < 128u) {
        int rbase = yy * 128 + x0;
        r[rr][0] = (x0 > 0) ? b2f(plane[rbase - 1]) : 0.f;
        uint4 v = *(const uint4*)&plane[rbase];
        u32 ws[4] = {v.x, v.y, v.z, v.w};
#pragma unroll
        for (int j = 0; j < 4; ++j) {
          r[rr][1 + 2 * j] = b2f((u16)(ws[j] & 0xffff));
          r[rr][2 + 2 * j] = b2f((u16)(ws[j] >> 16));
        }
        r[rr][9] = (x0 < 120) ? b2f(plane[rbase + 8]) : 0.f;
      } else {
#pragma unroll
        for (int j = 0; j < 10; ++j) r[rr][j] = 0.f;
      }
    }

    u32 packed[4];
#pragma unroll
    for (int j = 0; j < 8; ++j) {
      float a = 0.f;
#pragma unroll
      for (int rr = 0; rr < 3; ++rr)
#pragma unroll
        for (int dx = 0; dx < 3; ++dx)
          a += w[rr * 3 + dx] * r[rr][j + dx];
      u16 h = f2b(a);
      float hv = b2f(h);
      ns += hv * hv;
      if (j & 1) packed[j >> 1] |= ((u32)h) << 16; else packed[j >> 1] = (u32)h;
    }
    gdst[idx] = make_uint4(packed[0], packed[1], packed[2], packed[3]);
  }

  red[tid] = ns;
  __syncthreads();
  for (int st = 128; st > 0; st >>= 1) {
    if (tid < st) red[tid] += red[tid + st];
    __syncthreads();
  }
  if (tid == 0) {
    float n = sqrtf(red[0]);
    float inv = 1.f / fmaxf(n, 1e-12f);
    if (isQ) rnq[b * 384 + cc] = inv;
    else if (cc < 96) rnk[b * 96 + cc] = inv;
  }
}

// ---------------------------------------------------------------------------
// k5b: transpose v (kvd rows 96..191) -> vt [b][p][96] bf16. grid (64, 8).
// ---------------------------------------------------------------------------
__global__ void k5b_vt(const u16* __restrict__ kvd, u16* __restrict__ vt) {
  int p = blockIdx.x * 256 + threadIdx.x;
  int b = blockIdx.y;
  size_t sb = ((size_t)(b * KVC + 96)) * HW + p;
  uint4* dv = (uint4*)vt + ((size_t)(b * HW + p)) * 12;
  for (int j8 = 0; j8 < 12; ++j8) {
    u32 w[4];
#pragma unroll
    for (int j = 0; j < 8; ++j) {
      u16 h = kvd[sb + (size_t)(j8 * 8 + j) * HW];
      if (j & 1) w[j >> 1] |= ((u32)h) << 16; else w[j >> 1] = (u32)h;
    }
    dv[j8] = make_uint4(w[0], w[1], w[2], w[3]);
  }
}

// ---------------------------------------------------------------------------
// k6: split-K QK^T partials. grid (16, 8, 8).
// ---------------------------------------------------------------------------
__global__ __launch_bounds__(256) void k6_qk(const u16* __restrict__ qd,
                                             const u16* __restrict__ kvd,
                                             float* __restrict__ spart) {
  int kc = blockIdx.x, h = blockIdx.y, b = blockIdx.z;
  int tid = threadIdx.x;
  int w = tid >> 6, l = tid & 63, lr = l & 15, lg = l >> 4;
  int g = h >> 2;
  int p0 = kc * 1024 + w * 256;

  f32x4 acc[3][3] = {};
  size_t qbase = ((size_t)(b * CDIM + h * 48 + lr)) * HW;
  size_t kbase = ((size_t)(b * KVC + g * 48 + lr)) * HW;

  for (int ks = 0; ks < 8; ++ks) {
    int pp = p0 + ks * 32 + lg * 8;
    s16x8 a[3], bb[3];
#pragma unroll
    for (int mi = 0; mi < 3; ++mi) a[mi] = *(const s16x8*)(qd + qbase + (size_t)mi * 16 * HW + pp);
#pragma unroll
    for (int ni = 0; ni < 3; ++ni) bb[ni] = *(const s16x8*)(kvd + kbase + (size_t)ni * 16 * HW + pp);
#pragma unroll
    for (int mi = 0; mi < 3; ++mi)
#pragma unroll
      for (int ni = 0; ni < 3; ++ni)
        acc[mi][ni] = __builtin_amdgcn_mfma_f32_16x16x32_bf16(a[mi], bb[ni], acc[mi][ni], 0, 0, 0);
  }

  size_t sb = ((size_t)((((b * 8 + h) * 16) + kc) * 4 + w)) * 2304;
#pragma unroll
  for (int mi = 0; mi < 3; ++mi)
#pragma unroll
    for (int ni = 0; ni < 3; ++ni)
#pragma unroll
      for (int r = 0; r < 4; ++r) {
        int c = mi * 16 + lg * 4 + r, d = ni * 16 + lr;
        spart[sb + c * 48 + d] = acc[mi][ni][r];
      }
}

// ---------------------------------------------------------------------------
// k7: reduce partials + scale + softmax -> P~ [b][384][96] bf16.
// ---------------------------------------------------------------------------
__global__ void k7_sm(const float* __restrict__ spart, const float* __restrict__ temp,
                      const float* __restrict__ rnq, const float* __restrict__ rnk,
                      u16* __restrict__ ptil) {
  int h = blockIdx.x, b = blockIdx.y, tid = threadIdx.x;
  int g = h >> 2;
  __shared__ float S[2304];
  size_t base = ((size_t)((b * 8 + h) * 64)) * 2304;
  for (int e = tid; e < 2304; e += 64) {
    float s = 0.f;
    for (int j = 0; j < 64; ++j) s += spart[base + (size_t)j * 2304 + e];
    S[e] = s;
  }
  __syncthreads();
  if (tid < 48) {
    int c = tid;
    float sq = temp[h] * rnq[b * 384 + h * 48 + c];
    float mx = -1e30f;
    for (int d = 0; d < 48; ++d) {
      float v = S[c * 48 + d] * sq * rnk[b * 96 + g * 48 + d];
      mx = fmaxf(mx, v);
    }
    float sum = 0.f;
    for (int d = 0; d < 48; ++d) {
      float v = S[c * 48 + d] * sq * rnk[b * 96 + g * 48 + d];
      sum += __expf(v - mx);
    }
    float inv = 1.f / sum;
    u16* row = ptil + ((size_t)(b * 384 + h * 48 + c)) * 96;
    for (int dk = 0; dk < 96; ++dk) {
      int d = dk - g * 48;
      float pv = 0.f;
      if (d >= 0 && d < 48) {
        float v = S[c * 48 + d] * sq * rnk[b * 96 + g * 48 + d];
        pv = __expf(v - mx) * inv;
      }
      row[dk] = f2b(pv);
    }
  }
}

// ---------------------------------------------------------------------------
// k8: Yt[p][c] = sum_dk vt[p][dk] * P~[c][dk].  grid (128, 8), 512 thr.
// ---------------------------------------------------------------------------
__global__ __launch_bounds__(512) void k8_pv(const u16* __restrict__ vt,
                                             const u16* __restrict__ ptil,
                                             u16* __restrict__ yt) {
  int ptb = blockIdx.x, b = blockIdx.y;
  int tid = threadIdx.x;
  int w = tid >> 6, l = tid & 63, lr = l & 15, lg = l >> 4;
  int wm = w >> 2, wn = w & 3;

  f32x4 acc[4][6] = {};
  size_t arow0 = ((size_t)(b * HW + ptb * 128 + wm * 64 + lr)) * 96;
  size_t brow0 = ((size_t)(b * CDIM + wn * 96 + lr)) * 96;

  for (int ks = 0; ks < 3; ++ks) {
    int ko = ks * 32 + lg * 8;
    s16x8 a[4], bb[6];
#pragma unroll
    for (int mf = 0; mf < 4; ++mf) a[mf] = *(const s16x8*)(vt + arow0 + (size_t)mf * 16 * 96 + ko);
#pragma unroll
    for (int nf = 0; nf < 6; ++nf) bb[nf] = *(const s16x8*)(ptil + brow0 + (size_t)nf * 16 * 96 + ko);
#pragma unroll
    for (int mf = 0; mf < 4; ++mf)
#pragma unroll
      for (int nf = 0; nf < 6; ++nf)
        acc[mf][nf] = __builtin_amdgcn_mfma_f32_16x16x32_bf16(a[mf], bb[nf], acc[mf][nf], 0, 0, 0);
  }

#pragma unroll
  for (int mf = 0; mf < 4; ++mf)
#pragma unroll
    for (int nf = 0; nf < 6; ++nf)
#pragma unroll
      for (int r = 0; r < 4; ++r) {
        int p = ptb * 128 + wm * 64 + mf * 16 + lg * 4 + r;
        int c = wn * 96 + nf * 16 + lr;
        yt[((size_t)(b * HW + p)) * 384 + c] = f2b(acc[mf][nf][r]);
      }
}

// ---------------------------------------------------------------------------
extern "C" void kernel_launch(void* const* d_in, const int* in_sizes, int n_in,
                              void* d_out, int out_size, void* d_ws, size_t ws_size,
                              hipStream_t stream) {
  const float* q    = (const float*)d_in[0];
  const float* k    = (const float*)d_in[1];
  const float* w_q  = (const float*)d_in[2];
  const float* w_kv = (const float*)d_in[3];
  const float* w_qd = (const float*)d_in[4];
  const float* w_kd = (const float*)d_in[5];
  const float* w_o  = (const float*)d_in[6];
  const float* temp = (const float*)d_in[7];
  const float* lnqw = (const float*)d_in[8];
  const float* lnqb = (const float*)d_in[9];
  const float* lnkw = (const float*)d_in[10];
  const float* lnkb = (const float*)d_in[11];
  float* out = (float*)d_out;

  char* ws = (char*)d_ws;
  size_t off = 0;
  auto alloc = [&](size_t bytes) -> void* {
    void* p = ws + off;
    off += (bytes + 255) & ~(size_t)255;
    return p;
  };

  u16*   wqp   = (u16*)alloc(384 * 384 * 2);
  float* rwsQ  = (float*)alloc(384 * 4);
  float* biasQ = (float*)alloc(384 * 4);
  u16*   wkvp  = (u16*)alloc(256 * 384 * 2);   // padded to 256 rows
  float* rwsKV = (float*)alloc(256 * 4);
  float* biasKV= (float*)alloc(256 * 4);
  u16*   wop   = (u16*)alloc(384 * 384 * 2);
  u16*   qp    = (u16*)alloc((size_t)NB * CDIM * HW * 2);  // aliased as yt later
  u16*   kvp   = (u16*)alloc((size_t)NB * KVC * HW * 2);
  u16*   qd    = (u16*)alloc((size_t)NB * CDIM * HW * 2);
  u16*   kvd   = (u16*)alloc((size_t)NB * KVC * HW * 2);
  u16*   vt    = (u16*)alloc((size_t)NB * HW * 96 * 2);
  float* spart = (float*)alloc((size_t)4096 * 2304 * 4);
  u16*   ptil  = (u16*)alloc((size_t)NB * CDIM * 96 * 2);
  float* rnq   = (float*)alloc((size_t)NB * 384 * 4);
  float* rnk   = (float*)alloc((size_t)NB * 96 * 4);

  // lifetime alias (sequential stream => safe): qp dead after k4
  u16* yt = qp;

  k0_prep<<<4, 256, 0, stream>>>(w_q, w_kv, w_o, lnqw, lnqb, lnkw, lnkb,
                                 wqp, rwsQ, biasQ, wkvp, rwsKV, biasKV, wop);

  gemm_fused<0><<<dim3(256, 3, NB), 256, 0, stream>>>(wqp, q, rwsQ, biasQ, qp, 384);
  gemm_fused<0><<<dim3(256, 2, NB), 256, 0, stream>>>(wkvp, k, rwsKV, biasKV, kvp, 192);

  k4_dw<<<dim3(576, NB), 256, 0, stream>>>(qp, kvp, w_qd, w_kd, qd, kvd, rnq, rnk);

  k5b_vt<<<dim3(64, NB), 256, 0, stream>>>(kvd, vt);

  k6_qk<<<dim3(16, 8, NB), 256, 0, stream>>>(qd, kvd, spart);
  k7_sm<<<dim3(8, NB), 64, 0, stream>>>(spart, temp, rnq, rnk, ptil);

  k8_pv<<<dim3(128, NB), 512, 0, stream>>>(vt, ptil, yt);

  gemm_fused<1><<<dim3(256, 3, NB), 256, 0, stream>>>(wop, yt, nullptr, nullptr, out, 384);
}